// Round 4
// baseline (294.485 us; speedup 1.0000x reference)
//
#include <hip/hip_runtime.h>
#include <stdint.h>

#define HEADS 4
#define DHEAD 32
#define NTOK  4096
#define CDIM  256
#define HID   128
#define NBATCH 4

typedef __bf16 bf16x8 __attribute__((ext_vector_type(8)));
typedef __bf16 bf16x4 __attribute__((ext_vector_type(4)));
typedef float  f32x4  __attribute__((ext_vector_type(4)));

// softmax scale folded with log2(e) into Q so scores are in base-2 domain
#define QSCALE (0.17677669529663689f * 1.4426950408889634f)

#define MFMA __builtin_amdgcn_mfma_f32_16x16x32_bf16

// ---------------------------------------------------------------------------
// cast_x: x[b][c][p] f32 -> Xt[b][p][c] bf16   (transpose via LDS)
// ---------------------------------------------------------------------------
__global__ __launch_bounds__(256) void cast_x(const float* __restrict__ x,
                                              __bf16* __restrict__ Xt)
{
    __shared__ float xs[64][65];
    const int t = threadIdx.x;
    const int p0 = blockIdx.x * 64;      // 64 tiles
    const int c0 = blockIdx.y * 64;      // 4 tiles
    const int b  = blockIdx.z;           // 4
#pragma unroll
    for (int k = 0; k < 16; ++k) {
        int e = t + k * 256, c = e >> 6, p = e & 63;
        xs[c][p] = x[((size_t)(b * CDIM + c0 + c)) * NTOK + p0 + p];
    }
    __syncthreads();
#pragma unroll
    for (int k = 0; k < 16; ++k) {
        int e = t + k * 256, p = e >> 6, c = e & 63;
        Xt[((size_t)(b * NTOK + p0 + p)) * CDIM + c0 + c] = (__bf16)xs[c][p];
    }
}

// ---------------------------------------------------------------------------
// cast_w: w_qkv (384x256) and w_out (256x128) f32 -> bf16
// ---------------------------------------------------------------------------
__global__ __launch_bounds__(256) void cast_w(const float* __restrict__ wq,
                                              const float* __restrict__ wo,
                                              __bf16* __restrict__ Wq,
                                              __bf16* __restrict__ Wo)
{
    int e = blockIdx.x * 256 + threadIdx.x;      // 512 blocks = 131072
    if (e < 384 * 256) Wq[e] = (__bf16)wq[e];
    else               Wo[e - 384 * 256] = (__bf16)wo[e - 384 * 256];
}

// ---------------------------------------------------------------------------
// qkv_gemm: C[o,p] = sum_c Wq[o,c] * X[c,p]  (per batch), o in [0,384)
//   Q,K: [bh][p][32] bf16 (Q pre-scaled);  Vt: [bh][32][4096] bf16
// ---------------------------------------------------------------------------
__global__ __launch_bounds__(256) void qkv_gemm(
    const __bf16* __restrict__ Wq, const __bf16* __restrict__ Xt,
    __bf16* __restrict__ Q, __bf16* __restrict__ K, __bf16* __restrict__ Vt)
{
    const int t = threadIdx.x;
    const int pt = blockIdx.x;           // 32 (128 p each)
    const int ot = blockIdx.y;           // 6  (64 o each)
    const int b  = blockIdx.z;           // 4
    const int w = t >> 6, l = t & 63, lm = l & 15, q4 = l >> 4;
    const int pw0 = pt * 128 + w * 32;

    const __bf16* xb0 = Xt + ((size_t)(b * NTOK + pw0 + lm)) * CDIM + q4 * 8;
    const __bf16* xb1 = xb0 + 16 * CDIM;
    const __bf16* wa  = Wq + ((size_t)(ot * 64 + lm)) * CDIM + q4 * 8;

    f32x4 acc[4][2] = {};
#pragma unroll
    for (int kt = 0; kt < 8; ++kt) {
        bf16x8 b0 = *(const bf16x8*)(xb0 + kt * 32);
        bf16x8 b1 = *(const bf16x8*)(xb1 + kt * 32);
#pragma unroll
        for (int mt = 0; mt < 4; ++mt) {
            bf16x8 af = *(const bf16x8*)(wa + (size_t)mt * 16 * CDIM + kt * 32);
            acc[mt][0] = MFMA(af, b0, acc[mt][0], 0, 0, 0);
            acc[mt][1] = MFMA(af, b1, acc[mt][1], 0, 0, 0);
        }
    }

    const int obase = ot * 64;
#pragma unroll
    for (int mt = 0; mt < 4; ++mt) {
        int og0  = obase + mt * 16 + q4 * 4;      // r=0..3 stay in one head
        int which = og0 >> 7;                      // uniform per (ot,mt)
        int head  = (og0 >> 5) & 3;
        int d0    = og0 & 31;
        int bh    = b * HEADS + head;
#pragma unroll
        for (int n16 = 0; n16 < 2; ++n16) {
            int p_g = pw0 + n16 * 16 + lm;
            f32x4 a = acc[mt][n16];
            if (which == 0) {
                bf16x4 pk = { (__bf16)(a[0] * QSCALE), (__bf16)(a[1] * QSCALE),
                              (__bf16)(a[2] * QSCALE), (__bf16)(a[3] * QSCALE) };
                *(bf16x4*)(Q + ((size_t)bh * NTOK + p_g) * DHEAD + d0) = pk;
            } else if (which == 1) {
                bf16x4 pk = { (__bf16)a[0], (__bf16)a[1], (__bf16)a[2], (__bf16)a[3] };
                *(bf16x4*)(K + ((size_t)bh * NTOK + p_g) * DHEAD + d0) = pk;
            } else {
#pragma unroll
                for (int r = 0; r < 4; ++r)
                    Vt[((size_t)(bh * DHEAD + d0 + r)) * NTOK + p_g] = (__bf16)a[r];
            }
        }
    }
}

// ---------------------------------------------------------------------------
// attn: flash attention, no-max softmax, split-j x2, VALU-minimized:
//  - row-sums via ones-column MFMA (o2) instead of scalar adds/shuffles
//  - 512-thread blocks (8 waves) to probe the ~4-workgroups/CU residency cap
// Writes UNNORMALIZED fp32 partial O + fp32 partial row-sums (from o2).
// ---------------------------------------------------------------------------
__global__ __launch_bounds__(512) void attn(
    const __bf16* __restrict__ Q, const __bf16* __restrict__ K,
    const __bf16* __restrict__ Vt, float* __restrict__ Opart,
    float* __restrict__ Lsum)
{
    __shared__ __bf16 Ps[8][16][72];               // per-wave P rows (i=lm)

    const int t   = threadIdx.x;
    const int blk = blockIdx.x;                    // 1024
    const int bh  = blk & 15;
    const int rest = blk >> 4;                     // 0..63
    const int qb   = rest & 31;                    // 32 tiles of 128 rows
    const int half = rest >> 5;                    // j-split
    const int w = t >> 6, l = t & 63, lm = l & 15, q4 = l >> 4;
    const int row0 = qb * 128 + w * 16;

    // Q fragment (pre-scaled): lane holds Q[i=lm][d = q4*8..+7]
    bf16x8 qf = *(const bf16x8*)(Q + ((size_t)bh * NTOK + row0 + lm) * DHEAD + q4 * 8);
    const __bf16* Kb = K  + ((size_t)bh * NTOK + half * 2048) * DHEAD
                          + ((size_t)lm) * DHEAD + q4 * 8;
    const __bf16* Vb = Vt + (size_t)bh * DHEAD * NTOK + half * 2048
                          + ((size_t)lm) * NTOK + q4 * 8;

    bf16x8 ones;
#pragma unroll
    for (int u = 0; u < 8; ++u) ones[u] = (__bf16)1.0f;

    f32x4 o0 = {}, o1 = {}, o2 = {};

    for (int jt = 0; jt < 32; ++jt) {
        // S^T tiles: rows j, col i = lm   (A=K rows, B=Q rows; layouts match)
        f32x4 st[4];
#pragma unroll
        for (int j4 = 0; j4 < 4; ++j4) {
            bf16x8 kf = *(const bf16x8*)(Kb + (size_t)j4 * 16 * DHEAD);
            f32x4 z = {};
            st[j4] = MFMA(kf, qf, z, 0, 0, 0);
        }
        // exp2 -> bf16 -> LDS (4 consecutive j per lane -> b64 store)
#pragma unroll
        for (int j4 = 0; j4 < 4; ++j4) {
            bf16x4 pk;
            pk[0] = (__bf16)__builtin_amdgcn_exp2f(st[j4][0]);
            pk[1] = (__bf16)__builtin_amdgcn_exp2f(st[j4][1]);
            pk[2] = (__bf16)__builtin_amdgcn_exp2f(st[j4][2]);
            pk[3] = (__bf16)__builtin_amdgcn_exp2f(st[j4][3]);
            *(bf16x4*)&Ps[w][lm][j4 * 16 + q4 * 4] = pk;
        }
        // O += P*V ; row-sums += P*1  (same MFMA pipe, C-layout matches O)
#pragma unroll
        for (int jc = 0; jc < 2; ++jc) {
            bf16x8 pf = *(const bf16x8*)&Ps[w][lm][jc * 32 + q4 * 8];
            bf16x8 v0 = *(const bf16x8*)(Vb + jc * 32);
            bf16x8 v1 = *(const bf16x8*)(Vb + (size_t)16 * NTOK + jc * 32);
            o0 = MFMA(pf, v0, o0, 0, 0, 0);
            o1 = MFMA(pf, v1, o1, 0, 0, 0);
            o2 = MFMA(pf, ones, o2, 0, 0, 0);
        }
        Kb += 64 * DHEAD;
        Vb += 64;
    }

    // o2[r] = row-sum of P for row i = q4*4+r (identical across lm)
    if (lm == 0)
        *(f32x4*)(Lsum + ((size_t)half * 16 + bh) * NTOK + row0 + q4 * 4) = o2;

    // write UNNORMALIZED partial O (fp32): lane reg r = O[i=q4*4+r][d=lm(+16)]
    const int b = bh >> 2, h = bh & 3;
    float* Op = Opart + (size_t)half * NBATCH * NTOK * HID;
#pragma unroll
    for (int r = 0; r < 4; ++r) {
        size_t rowg = (size_t)b * NTOK + row0 + q4 * 4 + r;
        Op[rowg * HID + h * DHEAD + lm]      = o0[r];
        Op[rowg * HID + h * DHEAD + 16 + lm] = o1[r];
    }
}

// ---------------------------------------------------------------------------
// out_gemm: out[b,o,p] = bias[o] + sum_c Wo[o,c] * (O0+O1)[b,p,c] / L[b,head(c),p]
// ---------------------------------------------------------------------------
__global__ __launch_bounds__(256) void out_gemm(
    const __bf16* __restrict__ Wo, const float* __restrict__ O0,
    const float* __restrict__ O1, const float* __restrict__ L0,
    const float* __restrict__ L1, const float* __restrict__ bias,
    float* __restrict__ out)
{
    const int t = threadIdx.x;
    const int pt = blockIdx.x;           // 32
    const int ot = blockIdx.y;           // 4 (64 o each)
    const int b  = blockIdx.z;           // 4
    const int w = t >> 6, l = t & 63, lm = l & 15, q4 = l >> 4;
    const int pw0 = pt * 128 + w * 32;

    const int p0g = pw0 + lm, p1g = p0g + 16;
    const size_t base0 = ((size_t)(b * NTOK + p0g)) * HID + q4 * 8;
    const size_t base1 = base0 + (size_t)16 * HID;
    const __bf16* wa = Wo + ((size_t)(ot * 64 + lm)) * HID + q4 * 8;

    f32x4 acc[4][2] = {};
#pragma unroll
    for (int kt = 0; kt < 4; ++kt) {     // kt == head for this c-chunk
        const size_t lb = ((size_t)(b * HEADS + kt)) * NTOK;
        float inv0 = 1.f / (L0[lb + p0g] + L1[lb + p0g]);
        float inv1 = 1.f / (L0[lb + p1g] + L1[lb + p1g]);

        f32x4 a0 = *(const f32x4*)(O0 + base0 + kt * 32);
        f32x4 a1 = *(const f32x4*)(O0 + base0 + kt * 32 + 4);
        f32x4 c0 = *(const f32x4*)(O1 + base0 + kt * 32);
        f32x4 c1 = *(const f32x4*)(O1 + base0 + kt * 32 + 4);
        bf16x8 b0;
#pragma unroll
        for (int u = 0; u < 4; ++u) {
            b0[u]     = (__bf16)((a0[u] + c0[u]) * inv0);
            b0[u + 4] = (__bf16)((a1[u] + c1[u]) * inv0);
        }
        a0 = *(const f32x4*)(O0 + base1 + kt * 32);
        a1 = *(const f32x4*)(O0 + base1 + kt * 32 + 4);
        c0 = *(const f32x4*)(O1 + base1 + kt * 32);
        c1 = *(const f32x4*)(O1 + base1 + kt * 32 + 4);
        bf16x8 b1;
#pragma unroll
        for (int u = 0; u < 4; ++u) {
            b1[u]     = (__bf16)((a0[u] + c0[u]) * inv1);
            b1[u + 4] = (__bf16)((a1[u] + c1[u]) * inv1);
        }
#pragma unroll
        for (int mt = 0; mt < 4; ++mt) {
            bf16x8 af = *(const bf16x8*)(wa + (size_t)mt * 16 * HID + kt * 32);
            acc[mt][0] = MFMA(af, b0, acc[mt][0], 0, 0, 0);
            acc[mt][1] = MFMA(af, b1, acc[mt][1], 0, 0, 0);
        }
    }

#pragma unroll
    for (int mt = 0; mt < 4; ++mt) {
        int og0 = ot * 64 + mt * 16 + q4 * 4;
#pragma unroll
        for (int n16 = 0; n16 < 2; ++n16) {
            int p_g = pw0 + n16 * 16 + lm;
#pragma unroll
            for (int r = 0; r < 4; ++r)
                out[((size_t)(b * CDIM + og0 + r)) * NTOK + p_g] =
                    acc[mt][n16][r] + bias[og0 + r];
        }
    }
}

// ---------------------------------------------------------------------------
extern "C" void kernel_launch(void* const* d_in, const int* in_sizes, int n_in,
                              void* d_out, int out_size, void* d_ws, size_t ws_size,
                              hipStream_t stream)
{
    const float* x     = (const float*)d_in[0];
    const float* w_qkv = (const float*)d_in[1];
    const float* w_out = (const float*)d_in[2];
    const float* b_out = (const float*)d_in[3];
    float* out = (float*)d_out;

    __bf16* Xt = (__bf16*)d_ws;                     // 8 MB
    __bf16* Wq = Xt + (size_t)NBATCH * NTOK * CDIM;
    __bf16* Wo = Wq + 384 * 256;
    __bf16* Q  = Wo + 256 * 128;                    // 4 MB each
    __bf16* K  = Q  + (size_t)16 * NTOK * DHEAD;
    __bf16* Vt = K  + (size_t)16 * NTOK * DHEAD;
    float*  Opart = (float*)(Vt + (size_t)16 * NTOK * DHEAD);  // 2 x 8 MB
    float*  Lsum  = Opart + (size_t)2 * NBATCH * NTOK * HID;   // 2 x 256 KB
    float*  L1p   = Lsum + (size_t)16 * NTOK;
    float*  O1p   = Opart + (size_t)NBATCH * NTOK * HID;

    cast_x  <<<dim3(64, 4, NBATCH), 256, 0, stream>>>(x, Xt);
    cast_w  <<<512, 256, 0, stream>>>(w_qkv, w_out, Wq, Wo);
    qkv_gemm<<<dim3(32, 6, NBATCH), 256, 0, stream>>>(Wq, Xt, Q, K, Vt);
    attn    <<<1024, 512, 0, stream>>>(Q, K, Vt, Opart, Lsum);
    out_gemm<<<dim3(32, 4, NBATCH), 256, 0, stream>>>(Wo, Opart, O1p, Lsum, L1p, b_out, out);
}

// Round 5
// 288.402 us; speedup vs baseline: 1.0211x; 1.0211x over previous
//
#include <hip/hip_runtime.h>
#include <stdint.h>

#define HEADS 4
#define DHEAD 32
#define NTOK  4096
#define CDIM  256
#define HID   128
#define NBATCH 4

typedef __bf16 bf16x8 __attribute__((ext_vector_type(8)));
typedef __bf16 bf16x4 __attribute__((ext_vector_type(4)));
typedef float  f32x4  __attribute__((ext_vector_type(4)));

// softmax scale folded with log2(e) into Q so scores are in base-2 domain
#define QSCALE (0.17677669529663689f * 1.4426950408889634f)

#define MFMA __builtin_amdgcn_mfma_f32_16x16x32_bf16

// ---------------------------------------------------------------------------
// cast_x: x[b][c][p] f32 -> Xt[b][p][c] bf16   (transpose via LDS)
// ---------------------------------------------------------------------------
__global__ __launch_bounds__(256) void cast_x(const float* __restrict__ x,
                                              __bf16* __restrict__ Xt)
{
    __shared__ float xs[64][65];
    const int t = threadIdx.x;
    const int p0 = blockIdx.x * 64;      // 64 tiles
    const int c0 = blockIdx.y * 64;      // 4 tiles
    const int b  = blockIdx.z;           // 4
#pragma unroll
    for (int k = 0; k < 16; ++k) {
        int e = t + k * 256, c = e >> 6, p = e & 63;
        xs[c][p] = x[((size_t)(b * CDIM + c0 + c)) * NTOK + p0 + p];
    }
    __syncthreads();
#pragma unroll
    for (int k = 0; k < 16; ++k) {
        int e = t + k * 256, p = e >> 6, c = e & 63;
        Xt[((size_t)(b * NTOK + p0 + p)) * CDIM + c0 + c] = (__bf16)xs[c][p];
    }
}

// ---------------------------------------------------------------------------
// cast_w: w_qkv (384x256) and w_out (256x128) f32 -> bf16
// ---------------------------------------------------------------------------
__global__ __launch_bounds__(256) void cast_w(const float* __restrict__ wq,
                                              const float* __restrict__ wo,
                                              __bf16* __restrict__ Wq,
                                              __bf16* __restrict__ Wo)
{
    int e = blockIdx.x * 256 + threadIdx.x;      // 512 blocks = 131072
    if (e < 384 * 256) Wq[e] = (__bf16)wq[e];
    else               Wo[e - 384 * 256] = (__bf16)wo[e - 384 * 256];
}

// ---------------------------------------------------------------------------
// qkv_gemm: C[o,p] = sum_c Wq[o,c] * X[c,p]  (per batch), o in [0,384)
//   Q,K: [bh][p][32] bf16 (Q pre-scaled);  Vt: [bh][32][4096] bf16
// ---------------------------------------------------------------------------
__global__ __launch_bounds__(256) void qkv_gemm(
    const __bf16* __restrict__ Wq, const __bf16* __restrict__ Xt,
    __bf16* __restrict__ Q, __bf16* __restrict__ K, __bf16* __restrict__ Vt)
{
    const int t = threadIdx.x;
    const int pt = blockIdx.x;           // 32 (128 p each)
    const int ot = blockIdx.y;           // 6  (64 o each)
    const int b  = blockIdx.z;           // 4
    const int w = t >> 6, l = t & 63, lm = l & 15, q4 = l >> 4;
    const int pw0 = pt * 128 + w * 32;

    const __bf16* xb0 = Xt + ((size_t)(b * NTOK + pw0 + lm)) * CDIM + q4 * 8;
    const __bf16* xb1 = xb0 + 16 * CDIM;
    const __bf16* wa  = Wq + ((size_t)(ot * 64 + lm)) * CDIM + q4 * 8;

    f32x4 acc[4][2] = {};
#pragma unroll
    for (int kt = 0; kt < 8; ++kt) {
        bf16x8 b0 = *(const bf16x8*)(xb0 + kt * 32);
        bf16x8 b1 = *(const bf16x8*)(xb1 + kt * 32);
#pragma unroll
        for (int mt = 0; mt < 4; ++mt) {
            bf16x8 af = *(const bf16x8*)(wa + (size_t)mt * 16 * CDIM + kt * 32);
            acc[mt][0] = MFMA(af, b0, acc[mt][0], 0, 0, 0);
            acc[mt][1] = MFMA(af, b1, acc[mt][1], 0, 0, 0);
        }
    }

    const int obase = ot * 64;
#pragma unroll
    for (int mt = 0; mt < 4; ++mt) {
        int og0  = obase + mt * 16 + q4 * 4;      // r=0..3 stay in one head
        int which = og0 >> 7;                      // uniform per (ot,mt)
        int head  = (og0 >> 5) & 3;
        int d0    = og0 & 31;
        int bh    = b * HEADS + head;
#pragma unroll
        for (int n16 = 0; n16 < 2; ++n16) {
            int p_g = pw0 + n16 * 16 + lm;
            f32x4 a = acc[mt][n16];
            if (which == 0) {
                bf16x4 pk = { (__bf16)(a[0] * QSCALE), (__bf16)(a[1] * QSCALE),
                              (__bf16)(a[2] * QSCALE), (__bf16)(a[3] * QSCALE) };
                *(bf16x4*)(Q + ((size_t)bh * NTOK + p_g) * DHEAD + d0) = pk;
            } else if (which == 1) {
                bf16x4 pk = { (__bf16)a[0], (__bf16)a[1], (__bf16)a[2], (__bf16)a[3] };
                *(bf16x4*)(K + ((size_t)bh * NTOK + p_g) * DHEAD + d0) = pk;
            } else {
#pragma unroll
                for (int r = 0; r < 4; ++r)
                    Vt[((size_t)(bh * DHEAD + d0 + r)) * NTOK + p_g] = (__bf16)a[r];
            }
        }
    }
}

// ---------------------------------------------------------------------------
// attn: flash attention, no-max softmax, split-j x2.
// SOFTWARE-PIPELINED: next j-tile's 8 K/V fragment loads are issued at the
// top of each iteration and consumed one iteration later, so the ~200-400 cyc
// L2 latency overlaps the S->exp2->LDS->PV chain (R4 showed 36 VGPRs => the
// compiler serialized load->wait->use; this forces ~64 VGPRs of load buffer).
// Row-sums via ones-column MFMA.  Writes UNNORMALIZED fp32 partials.
// ---------------------------------------------------------------------------
__global__ __launch_bounds__(256, 4) void attn(
    const __bf16* __restrict__ Q, const __bf16* __restrict__ K,
    const __bf16* __restrict__ Vt, float* __restrict__ Opart,
    float* __restrict__ Lsum)
{
    __shared__ __bf16 Ps[4][16][72];               // per-wave P rows (i=lm)

    const int t   = threadIdx.x;
    const int blk = blockIdx.x;                    // 2048
    const int bh  = blk & 15;
    const int rest = blk >> 4;                     // 0..127
    const int qb   = rest & 63;
    const int half = rest >> 6;                    // j-split
    const int w = t >> 6, l = t & 63, lm = l & 15, q4 = l >> 4;
    const int row0 = qb * 64 + w * 16;

    // Q fragment (pre-scaled): lane holds Q[i=lm][d = q4*8..+7]
    bf16x8 qf = *(const bf16x8*)(Q + ((size_t)bh * NTOK + row0 + lm) * DHEAD + q4 * 8);
    const __bf16* Kb = K  + ((size_t)bh * NTOK + half * 2048 + lm) * DHEAD + q4 * 8;
    const __bf16* Vb = Vt + (size_t)bh * DHEAD * NTOK + half * 2048
                          + (size_t)lm * NTOK + q4 * 8;

    bf16x8 ones;
#pragma unroll
    for (int u = 0; u < 8; ++u) ones[u] = (__bf16)1.0f;

    f32x4 o0 = {}, o1 = {}, o2 = {};

    // prologue: fragments for jt = 0
    bf16x8 kc[4], vc[4], kn[4], vn[4];
#pragma unroll
    for (int j4 = 0; j4 < 4; ++j4)
        kc[j4] = *(const bf16x8*)(Kb + (size_t)j4 * 16 * DHEAD);
    vc[0] = *(const bf16x8*)(Vb);
    vc[1] = *(const bf16x8*)(Vb + (size_t)16 * NTOK);
    vc[2] = *(const bf16x8*)(Vb + 32);
    vc[3] = *(const bf16x8*)(Vb + (size_t)16 * NTOK + 32);

#pragma unroll 2
    for (int jt = 0; jt < 32; ++jt) {
        // issue next tile's loads first (consumed next iteration)
        const int jn = (jt + 1) & 31;              // wrap: last prefetch harmless
        const __bf16* Kp = Kb + (size_t)jn * 64 * DHEAD;
        const __bf16* Vp = Vb + jn * 64;
#pragma unroll
        for (int j4 = 0; j4 < 4; ++j4)
            kn[j4] = *(const bf16x8*)(Kp + (size_t)j4 * 16 * DHEAD);
        vn[0] = *(const bf16x8*)(Vp);
        vn[1] = *(const bf16x8*)(Vp + (size_t)16 * NTOK);
        vn[2] = *(const bf16x8*)(Vp + 32);
        vn[3] = *(const bf16x8*)(Vp + (size_t)16 * NTOK + 32);

        // S^T tiles from current K frags
        f32x4 st[4];
#pragma unroll
        for (int j4 = 0; j4 < 4; ++j4) {
            f32x4 z = {};
            st[j4] = MFMA(kc[j4], qf, z, 0, 0, 0);
        }
        // exp2 -> bf16 -> LDS (4 consecutive j per lane -> b64 store)
#pragma unroll
        for (int j4 = 0; j4 < 4; ++j4) {
            bf16x4 pk;
            pk[0] = (__bf16)__builtin_amdgcn_exp2f(st[j4][0]);
            pk[1] = (__bf16)__builtin_amdgcn_exp2f(st[j4][1]);
            pk[2] = (__bf16)__builtin_amdgcn_exp2f(st[j4][2]);
            pk[3] = (__bf16)__builtin_amdgcn_exp2f(st[j4][3]);
            *(bf16x4*)&Ps[w][lm][j4 * 16 + q4 * 4] = pk;
        }
        // O += P*V ; row-sums += P*1
#pragma unroll
        for (int jc = 0; jc < 2; ++jc) {
            bf16x8 pf = *(const bf16x8*)&Ps[w][lm][jc * 32 + q4 * 8];
            o0 = MFMA(pf, vc[jc * 2 + 0], o0, 0, 0, 0);
            o1 = MFMA(pf, vc[jc * 2 + 1], o1, 0, 0, 0);
            o2 = MFMA(pf, ones, o2, 0, 0, 0);
        }
#pragma unroll
        for (int u = 0; u < 4; ++u) { kc[u] = kn[u]; vc[u] = vn[u]; }
    }

    // o2[r] = row-sum of P for row i = q4*4+r (identical across lm)
    if (lm == 0)
        *(f32x4*)(Lsum + ((size_t)half * 16 + bh) * NTOK + row0 + q4 * 4) = o2;

    // write UNNORMALIZED partial O (fp32): lane reg r = O[i=q4*4+r][d=lm(+16)]
    const int b = bh >> 2, h = bh & 3;
    float* Op = Opart + (size_t)half * NBATCH * NTOK * HID;
#pragma unroll
    for (int r = 0; r < 4; ++r) {
        size_t rowg = (size_t)b * NTOK + row0 + q4 * 4 + r;
        Op[rowg * HID + h * DHEAD + lm]      = o0[r];
        Op[rowg * HID + h * DHEAD + 16 + lm] = o1[r];
    }
}

// ---------------------------------------------------------------------------
// out_gemm: out[b,o,p] = bias[o] + sum_c Wo[o,c] * (O0+O1)[b,p,c] / L[b,head(c),p]
// ---------------------------------------------------------------------------
__global__ __launch_bounds__(256) void out_gemm(
    const __bf16* __restrict__ Wo, const float* __restrict__ O0,
    const float* __restrict__ O1, const float* __restrict__ L0,
    const float* __restrict__ L1, const float* __restrict__ bias,
    float* __restrict__ out)
{
    const int t = threadIdx.x;
    const int pt = blockIdx.x;           // 32
    const int ot = blockIdx.y;           // 4 (64 o each)
    const int b  = blockIdx.z;           // 4
    const int w = t >> 6, l = t & 63, lm = l & 15, q4 = l >> 4;
    const int pw0 = pt * 128 + w * 32;

    const int p0g = pw0 + lm, p1g = p0g + 16;
    const size_t base0 = ((size_t)(b * NTOK + p0g)) * HID + q4 * 8;
    const size_t base1 = base0 + (size_t)16 * HID;
    const __bf16* wa = Wo + ((size_t)(ot * 64 + lm)) * HID + q4 * 8;

    f32x4 acc[4][2] = {};
#pragma unroll
    for (int kt = 0; kt < 4; ++kt) {     // kt == head for this c-chunk
        const size_t lb = ((size_t)(b * HEADS + kt)) * NTOK;
        float inv0 = 1.f / (L0[lb + p0g] + L1[lb + p0g]);
        float inv1 = 1.f / (L0[lb + p1g] + L1[lb + p1g]);

        f32x4 a0 = *(const f32x4*)(O0 + base0 + kt * 32);
        f32x4 a1 = *(const f32x4*)(O0 + base0 + kt * 32 + 4);
        f32x4 c0 = *(const f32x4*)(O1 + base0 + kt * 32);
        f32x4 c1 = *(const f32x4*)(O1 + base0 + kt * 32 + 4);
        bf16x8 b0;
#pragma unroll
        for (int u = 0; u < 4; ++u) {
            b0[u]     = (__bf16)((a0[u] + c0[u]) * inv0);
            b0[u + 4] = (__bf16)((a1[u] + c1[u]) * inv0);
        }
        a0 = *(const f32x4*)(O0 + base1 + kt * 32);
        a1 = *(const f32x4*)(O0 + base1 + kt * 32 + 4);
        c0 = *(const f32x4*)(O1 + base1 + kt * 32);
        c1 = *(const f32x4*)(O1 + base1 + kt * 32 + 4);
        bf16x8 b1;
#pragma unroll
        for (int u = 0; u < 4; ++u) {
            b1[u]     = (__bf16)((a0[u] + c0[u]) * inv1);
            b1[u + 4] = (__bf16)((a1[u] + c1[u]) * inv1);
        }
#pragma unroll
        for (int mt = 0; mt < 4; ++mt) {
            bf16x8 af = *(const bf16x8*)(wa + (size_t)mt * 16 * HID + kt * 32);
            acc[mt][0] = MFMA(af, b0, acc[mt][0], 0, 0, 0);
            acc[mt][1] = MFMA(af, b1, acc[mt][1], 0, 0, 0);
        }
    }

#pragma unroll
    for (int mt = 0; mt < 4; ++mt) {
        int og0 = ot * 64 + mt * 16 + q4 * 4;
#pragma unroll
        for (int n16 = 0; n16 < 2; ++n16) {
            int p_g = pw0 + n16 * 16 + lm;
#pragma unroll
            for (int r = 0; r < 4; ++r)
                out[((size_t)(b * CDIM + og0 + r)) * NTOK + p_g] =
                    acc[mt][n16][r] + bias[og0 + r];
        }
    }
}

// ---------------------------------------------------------------------------
extern "C" void kernel_launch(void* const* d_in, const int* in_sizes, int n_in,
                              void* d_out, int out_size, void* d_ws, size_t ws_size,
                              hipStream_t stream)
{
    const float* x     = (const float*)d_in[0];
    const float* w_qkv = (const float*)d_in[1];
    const float* w_out = (const float*)d_in[2];
    const float* b_out = (const float*)d_in[3];
    float* out = (float*)d_out;

    __bf16* Xt = (__bf16*)d_ws;                     // 8 MB
    __bf16* Wq = Xt + (size_t)NBATCH * NTOK * CDIM;
    __bf16* Wo = Wq + 384 * 256;
    __bf16* Q  = Wo + 256 * 128;                    // 4 MB each
    __bf16* K  = Q  + (size_t)16 * NTOK * DHEAD;
    __bf16* Vt = K  + (size_t)16 * NTOK * DHEAD;
    float*  Opart = (float*)(Vt + (size_t)16 * NTOK * DHEAD);  // 2 x 8 MB
    float*  Lsum  = Opart + (size_t)2 * NBATCH * NTOK * HID;   // 2 x 256 KB
    float*  L1p   = Lsum + (size_t)16 * NTOK;
    float*  O1p   = Opart + (size_t)NBATCH * NTOK * HID;

    cast_x  <<<dim3(64, 4, NBATCH), 256, 0, stream>>>(x, Xt);
    cast_w  <<<512, 256, 0, stream>>>(w_qkv, w_out, Wq, Wo);
    qkv_gemm<<<dim3(32, 6, NBATCH), 256, 0, stream>>>(Wq, Xt, Q, K, Vt);
    attn    <<<2048, 256, 0, stream>>>(Q, K, Vt, Opart, Lsum);
    out_gemm<<<dim3(32, 4, NBATCH), 256, 0, stream>>>(Wo, Opart, O1p, Lsum, L1p, b_out, out);
}

// Round 6
// 165.766 us; speedup vs baseline: 1.7765x; 1.7398x over previous
//
#include <hip/hip_runtime.h>
#include <stdint.h>

#define HEADS 4
#define DHEAD 32
#define NTOK  4096
#define CDIM  256
#define HID   128
#define NBATCH 4

typedef __bf16 bf16x8 __attribute__((ext_vector_type(8)));
typedef __bf16 bf16x4 __attribute__((ext_vector_type(4)));
typedef float  f32x4  __attribute__((ext_vector_type(4)));

// softmax scale folded with log2(e) into Q so scores are in base-2 domain
#define QSCALE (0.17677669529663689f * 1.4426950408889634f)

#define MFMA __builtin_amdgcn_mfma_f32_16x16x32_bf16

// async global->LDS DMA, 16B per lane; LDS dest = uniform base + lane*16
#define ASYNC16(gp, lp)                                                        \
    __builtin_amdgcn_global_load_lds(                                          \
        (const __attribute__((address_space(1))) unsigned int*)(gp),           \
        (__attribute__((address_space(3))) unsigned int*)(lp), 16, 0, 0)

// ---------------------------------------------------------------------------
// cast_x: x[b][c][p] f32 -> Xt[b][p][c] bf16   (transpose via LDS)
// ---------------------------------------------------------------------------
__global__ __launch_bounds__(256) void cast_x(const float* __restrict__ x,
                                              __bf16* __restrict__ Xt)
{
    __shared__ float xs[64][65];
    const int t = threadIdx.x;
    const int p0 = blockIdx.x * 64;      // 64 tiles
    const int c0 = blockIdx.y * 64;      // 4 tiles
    const int b  = blockIdx.z;           // 4
#pragma unroll
    for (int k = 0; k < 16; ++k) {
        int e = t + k * 256, c = e >> 6, p = e & 63;
        xs[c][p] = x[((size_t)(b * CDIM + c0 + c)) * NTOK + p0 + p];
    }
    __syncthreads();
#pragma unroll
    for (int k = 0; k < 16; ++k) {
        int e = t + k * 256, p = e >> 6, c = e & 63;
        Xt[((size_t)(b * NTOK + p0 + p)) * CDIM + c0 + c] = (__bf16)xs[c][p];
    }
}

// ---------------------------------------------------------------------------
// cast_w: w_qkv (384x256) and w_out (256x128) f32 -> bf16
// ---------------------------------------------------------------------------
__global__ __launch_bounds__(256) void cast_w(const float* __restrict__ wq,
                                              const float* __restrict__ wo,
                                              __bf16* __restrict__ Wq,
                                              __bf16* __restrict__ Wo)
{
    int e = blockIdx.x * 256 + threadIdx.x;      // 512 blocks = 131072
    if (e < 384 * 256) Wq[e] = (__bf16)wq[e];
    else               Wo[e - 384 * 256] = (__bf16)wo[e - 384 * 256];
}

// ---------------------------------------------------------------------------
// qkv_gemm: C[o,p] = sum_c Wq[o,c] * X[c,p]  (per batch), o in [0,384)
//   Q,K: [bh][p][32] bf16 (Q pre-scaled);  Vt: [bh][32][4096] bf16
// ---------------------------------------------------------------------------
__global__ __launch_bounds__(256) void qkv_gemm(
    const __bf16* __restrict__ Wq, const __bf16* __restrict__ Xt,
    __bf16* __restrict__ Q, __bf16* __restrict__ K, __bf16* __restrict__ Vt)
{
    const int t = threadIdx.x;
    const int pt = blockIdx.x;           // 32 (128 p each)
    const int ot = blockIdx.y;           // 6  (64 o each)
    const int b  = blockIdx.z;           // 4
    const int w = t >> 6, l = t & 63, lm = l & 15, q4 = l >> 4;
    const int pw0 = pt * 128 + w * 32;

    const __bf16* xb0 = Xt + ((size_t)(b * NTOK + pw0 + lm)) * CDIM + q4 * 8;
    const __bf16* xb1 = xb0 + 16 * CDIM;
    const __bf16* wa  = Wq + ((size_t)(ot * 64 + lm)) * CDIM + q4 * 8;

    f32x4 acc[4][2] = {};
#pragma unroll
    for (int kt = 0; kt < 8; ++kt) {
        bf16x8 b0 = *(const bf16x8*)(xb0 + kt * 32);
        bf16x8 b1 = *(const bf16x8*)(xb1 + kt * 32);
#pragma unroll
        for (int mt = 0; mt < 4; ++mt) {
            bf16x8 af = *(const bf16x8*)(wa + (size_t)mt * 16 * CDIM + kt * 32);
            acc[mt][0] = MFMA(af, b0, acc[mt][0], 0, 0, 0);
            acc[mt][1] = MFMA(af, b1, acc[mt][1], 0, 0, 0);
        }
    }

    const int obase = ot * 64;
#pragma unroll
    for (int mt = 0; mt < 4; ++mt) {
        int og0  = obase + mt * 16 + q4 * 4;      // r=0..3 stay in one head
        int which = og0 >> 7;                      // uniform per (ot,mt)
        int head  = (og0 >> 5) & 3;
        int d0    = og0 & 31;
        int bh    = b * HEADS + head;
#pragma unroll
        for (int n16 = 0; n16 < 2; ++n16) {
            int p_g = pw0 + n16 * 16 + lm;
            f32x4 a = acc[mt][n16];
            if (which == 0) {
                bf16x4 pk = { (__bf16)(a[0] * QSCALE), (__bf16)(a[1] * QSCALE),
                              (__bf16)(a[2] * QSCALE), (__bf16)(a[3] * QSCALE) };
                *(bf16x4*)(Q + ((size_t)bh * NTOK + p_g) * DHEAD + d0) = pk;
            } else if (which == 1) {
                bf16x4 pk = { (__bf16)a[0], (__bf16)a[1], (__bf16)a[2], (__bf16)a[3] };
                *(bf16x4*)(K + ((size_t)bh * NTOK + p_g) * DHEAD + d0) = pk;
            } else {
#pragma unroll
                for (int r = 0; r < 4; ++r)
                    Vt[((size_t)(bh * DHEAD + d0 + r)) * NTOK + p_g] = (__bf16)a[r];
            }
        }
    }
}

// ---------------------------------------------------------------------------
// attn v6: LDS-staged, double-buffered flash attention.
//  - K/V tiles DMA'd to LDS via global_load_lds (un-sinkable async; 0 VGPRs),
//    shared by all 4 waves (global traffic / 4 vs R5).
//  - XOR-swizzled gather (DMA forbids padding): K chunk c^((r>>1)&3),
//    V chunk c^(r&7) -> all fragment ds_reads are 2-way (free).
//  - 2 row-groups per wave (128 Q rows/block) amortize K/V fragment reads.
//  - no-max softmax; row-sums via ones-column MFMA; fp32 partials, split-j x2.
// ---------------------------------------------------------------------------
__global__ __launch_bounds__(256, 4) void attn(
    const __bf16* __restrict__ Q, const __bf16* __restrict__ K,
    const __bf16* __restrict__ Vt, float* __restrict__ Opart,
    float* __restrict__ Lsum)
{
    __shared__ uint4  KbufU[2][256];               // [buf][64 rows x 64 B]
    __shared__ uint4  VbufU[2][256];               // [buf][32 rows x 128 B]
    __shared__ __bf16 Ps[4][16][72];               // per-wave P rows (i=lm)

    const int t   = threadIdx.x;
    const int blk = blockIdx.x;                    // 1024
    const int bh  = blk & 15;
    const int rest = blk >> 4;                     // 0..63
    const int qt   = rest & 31;                    // 32 tiles of 128 rows
    const int half = rest >> 5;                    // j-split
    const int l = t & 63, lm = l & 15, q4 = l >> 4;
    const int wu = __builtin_amdgcn_readfirstlane(t >> 6);  // wave id, uniform
    const int row0 = qt * 128 + wu * 32;

    // Q fragments (pre-scaled): group g rows row0+g*16, lane holds row lm
    bf16x8 qf[2];
#pragma unroll
    for (int g = 0; g < 2; ++g)
        qf[g] = *(const bf16x8*)(Q + ((size_t)bh * NTOK + row0 + g * 16 + lm) * DHEAD + q4 * 8);

    const char* KbT = (const char*)(K  + (size_t)bh * NTOK * DHEAD);   // row j: 64 B
    const char* VbT = (const char*)(Vt + (size_t)bh * DHEAD * NTOK);   // row d: 8192 B
    const int jh = half * 2048;

    // per-wave DMA lane mapping (gather-swizzled)
    const int sK_r  = wu * 16 + (l >> 2);                  // K row this lane fetches
    const int sK_gc = (l & 3) ^ ((sK_r >> 1) & 3);         // K global chunk
    const int sV_r  = wu * 8 + (l >> 3);                   // V row
    const int sV_gc = (l & 7) ^ (sV_r & 7);                // V global chunk

    bf16x8 ones;
#pragma unroll
    for (int u = 0; u < 8; ++u) ones[u] = (__bf16)1.0f;

    f32x4 o[2][3] = {};                            // per group: o_lo, o_hi, rowsum

    // prologue: stage tile 0 into buf 0
    {
        const char* gk = KbT + (size_t)(jh + sK_r) * 64 + sK_gc * 16;
        ASYNC16(gk, (char*)&KbufU[0][0] + wu * 1024);
        const char* gv = VbT + (size_t)sV_r * (NTOK * 2) + (size_t)jh * 2 + sV_gc * 16;
        ASYNC16(gv, (char*)&VbufU[0][0] + wu * 1024);
    }
    __syncthreads();

    for (int jt = 0; jt < 32; ++jt) {
        const int buf = jt & 1;
        if (jt < 31) {                             // stage next tile (async)
            const int j0n = jh + (jt + 1) * 64;
            const char* gk = KbT + (size_t)(j0n + sK_r) * 64 + sK_gc * 16;
            ASYNC16(gk, (char*)&KbufU[buf ^ 1][0] + wu * 1024);
            const char* gv = VbT + (size_t)sV_r * (NTOK * 2) + (size_t)j0n * 2 + sV_gc * 16;
            ASYNC16(gv, (char*)&VbufU[buf ^ 1][0] + wu * 1024);
        }

        const __bf16* Kl = (const __bf16*)&KbufU[buf][0];
        const __bf16* Vl = (const __bf16*)&VbufU[buf][0];

        // K fragments (shared across both row-groups), swizzled read
        bf16x8 kf[4];
#pragma unroll
        for (int j4 = 0; j4 < 4; ++j4) {
            int jl = j4 * 16 + lm;
            int cs = q4 ^ ((jl >> 1) & 3);
            kf[j4] = *(const bf16x8*)(Kl + jl * 32 + cs * 8);
        }
        // V fragments (shared), swizzled read: rows d=lm and d=16+lm
        const int swv = lm & 7;
        bf16x8 vf[4];
        vf[0] = *(const bf16x8*)(Vl + lm * 64        + ((q4    ) ^ swv) * 8);
        vf[1] = *(const bf16x8*)(Vl + (16 + lm) * 64 + ((q4    ) ^ swv) * 8);
        vf[2] = *(const bf16x8*)(Vl + lm * 64        + ((4 + q4) ^ swv) * 8);
        vf[3] = *(const bf16x8*)(Vl + (16 + lm) * 64 + ((4 + q4) ^ swv) * 8);

#pragma unroll
        for (int g = 0; g < 2; ++g) {
            // S^T = K Q^T : lane holds col i=lm, rows j=q4*4+r per j4 block
            f32x4 st[4];
#pragma unroll
            for (int j4 = 0; j4 < 4; ++j4) {
                f32x4 z = {};
                st[j4] = MFMA(kf[j4], qf[g], z, 0, 0, 0);
            }
            // exp2 -> bf16 -> per-wave LDS (row-major per i)
#pragma unroll
            for (int j4 = 0; j4 < 4; ++j4) {
                bf16x4 pk;
                pk[0] = (__bf16)__builtin_amdgcn_exp2f(st[j4][0]);
                pk[1] = (__bf16)__builtin_amdgcn_exp2f(st[j4][1]);
                pk[2] = (__bf16)__builtin_amdgcn_exp2f(st[j4][2]);
                pk[3] = (__bf16)__builtin_amdgcn_exp2f(st[j4][3]);
                *(bf16x4*)&Ps[wu][lm][j4 * 16 + q4 * 4] = pk;
            }
            // O += P*V ; rowsum += P*1
#pragma unroll
            for (int jc = 0; jc < 2; ++jc) {
                bf16x8 pf = *(const bf16x8*)&Ps[wu][lm][jc * 32 + q4 * 8];
                o[g][0] = MFMA(pf, vf[jc * 2 + 0], o[g][0], 0, 0, 0);
                o[g][1] = MFMA(pf, vf[jc * 2 + 1], o[g][1], 0, 0, 0);
                o[g][2] = MFMA(pf, ones,           o[g][2], 0, 0, 0);
            }
        }
        __syncthreads();   // drains DMA (vmcnt0) + all waves done with cur buf
    }

    // epilogue: Lsum + unnormalized fp32 partial O
    const int b = bh >> 2, h = bh & 3;
    float* Op = Opart + (size_t)half * NBATCH * NTOK * HID;
#pragma unroll
    for (int g = 0; g < 2; ++g) {
        const int rowg0 = row0 + g * 16;
        if (lm == 0)
            *(f32x4*)(Lsum + ((size_t)half * 16 + bh) * NTOK + rowg0 + q4 * 4) = o[g][2];
#pragma unroll
        for (int r = 0; r < 4; ++r) {
            size_t rowg = (size_t)b * NTOK + rowg0 + q4 * 4 + r;
            Op[rowg * HID + h * DHEAD + lm]      = o[g][0][r];
            Op[rowg * HID + h * DHEAD + 16 + lm] = o[g][1][r];
        }
    }
}

// ---------------------------------------------------------------------------
// out_gemm: out[b,o,p] = bias[o] + sum_c Wo[o,c] * (O0+O1)[b,p,c] / L[b,head(c),p]
// ---------------------------------------------------------------------------
__global__ __launch_bounds__(256) void out_gemm(
    const __bf16* __restrict__ Wo, const float* __restrict__ O0,
    const float* __restrict__ O1, const float* __restrict__ L0,
    const float* __restrict__ L1, const float* __restrict__ bias,
    float* __restrict__ out)
{
    const int t = threadIdx.x;
    const int pt = blockIdx.x;           // 32
    const int ot = blockIdx.y;           // 4 (64 o each)
    const int b  = blockIdx.z;           // 4
    const int w = t >> 6, l = t & 63, lm = l & 15, q4 = l >> 4;
    const int pw0 = pt * 128 + w * 32;

    const int p0g = pw0 + lm, p1g = p0g + 16;
    const size_t base0 = ((size_t)(b * NTOK + p0g)) * HID + q4 * 8;
    const size_t base1 = base0 + (size_t)16 * HID;
    const __bf16* wa = Wo + ((size_t)(ot * 64 + lm)) * HID + q4 * 8;

    f32x4 acc[4][2] = {};
#pragma unroll
    for (int kt = 0; kt < 4; ++kt) {     // kt == head for this c-chunk
        const size_t lb = ((size_t)(b * HEADS + kt)) * NTOK;
        float inv0 = 1.f / (L0[lb + p0g] + L1[lb + p0g]);
        float inv1 = 1.f / (L0[lb + p1g] + L1[lb + p1g]);

        f32x4 a0 = *(const f32x4*)(O0 + base0 + kt * 32);
        f32x4 a1 = *(const f32x4*)(O0 + base0 + kt * 32 + 4);
        f32x4 c0 = *(const f32x4*)(O1 + base0 + kt * 32);
        f32x4 c1 = *(const f32x4*)(O1 + base0 + kt * 32 + 4);
        bf16x8 b0;
#pragma unroll
        for (int u = 0; u < 4; ++u) {
            b0[u]     = (__bf16)((a0[u] + c0[u]) * inv0);
            b0[u + 4] = (__bf16)((a1[u] + c1[u]) * inv0);
        }
        a0 = *(const f32x4*)(O0 + base1 + kt * 32);
        a1 = *(const f32x4*)(O0 + base1 + kt * 32 + 4);
        c0 = *(const f32x4*)(O1 + base1 + kt * 32);
        c1 = *(const f32x4*)(O1 + base1 + kt * 32 + 4);
        bf16x8 b1;
#pragma unroll
        for (int u = 0; u < 4; ++u) {
            b1[u]     = (__bf16)((a0[u] + c0[u]) * inv1);
            b1[u + 4] = (__bf16)((a1[u] + c1[u]) * inv1);
        }
#pragma unroll
        for (int mt = 0; mt < 4; ++mt) {
            bf16x8 af = *(const bf16x8*)(wa + (size_t)mt * 16 * HID + kt * 32);
            acc[mt][0] = MFMA(af, b0, acc[mt][0], 0, 0, 0);
            acc[mt][1] = MFMA(af, b1, acc[mt][1], 0, 0, 0);
        }
    }

#pragma unroll
    for (int mt = 0; mt < 4; ++mt) {
        int og0 = ot * 64 + mt * 16 + q4 * 4;
#pragma unroll
        for (int n16 = 0; n16 < 2; ++n16) {
            int p_g = pw0 + n16 * 16 + lm;
#pragma unroll
            for (int r = 0; r < 4; ++r)
                out[((size_t)(b * CDIM + og0 + r)) * NTOK + p_g] =
                    acc[mt][n16][r] + bias[og0 + r];
        }
    }
}

// ---------------------------------------------------------------------------
extern "C" void kernel_launch(void* const* d_in, const int* in_sizes, int n_in,
                              void* d_out, int out_size, void* d_ws, size_t ws_size,
                              hipStream_t stream)
{
    const float* x     = (const float*)d_in[0];
    const float* w_qkv = (const float*)d_in[1];
    const float* w_out = (const float*)d_in[2];
    const float* b_out = (const float*)d_in[3];
    float* out = (float*)d_out;

    __bf16* Xt = (__bf16*)d_ws;                     // 8 MB
    __bf16* Wq = Xt + (size_t)NBATCH * NTOK * CDIM;
    __bf16* Wo = Wq + 384 * 256;
    __bf16* Q  = Wo + 256 * 128;                    // 4 MB each
    __bf16* K  = Q  + (size_t)16 * NTOK * DHEAD;
    __bf16* Vt = K  + (size_t)16 * NTOK * DHEAD;
    float*  Opart = (float*)(Vt + (size_t)16 * NTOK * DHEAD);  // 2 x 8 MB
    float*  Lsum  = Opart + (size_t)2 * NBATCH * NTOK * HID;   // 2 x 256 KB
    float*  L1p   = Lsum + (size_t)16 * NTOK;
    float*  O1p   = Opart + (size_t)NBATCH * NTOK * HID;

    cast_x  <<<dim3(64, 4, NBATCH), 256, 0, stream>>>(x, Xt);
    cast_w  <<<512, 256, 0, stream>>>(w_qkv, w_out, Wq, Wo);
    qkv_gemm<<<dim3(32, 6, NBATCH), 256, 0, stream>>>(Wq, Xt, Q, K, Vt);
    attn    <<<1024, 256, 0, stream>>>(Q, K, Vt, Opart, Lsum);
    out_gemm<<<dim3(32, 4, NBATCH), 256, 0, stream>>>(Wo, Opart, O1p, Lsum, L1p, b_out, out);
}

// Round 7
// 150.095 us; speedup vs baseline: 1.9620x; 1.1044x over previous
//
#include <hip/hip_runtime.h>
#include <stdint.h>

#define HEADS 4
#define DHEAD 32
#define NTOK  4096
#define CDIM  256
#define HID   128
#define NBATCH 4

typedef __bf16 bf16x8 __attribute__((ext_vector_type(8)));
typedef __bf16 bf16x4 __attribute__((ext_vector_type(4)));
typedef float  f32x4  __attribute__((ext_vector_type(4)));

// softmax scale folded with log2(e) into Q so scores are in base-2 domain
#define QSCALE (0.17677669529663689f * 1.4426950408889634f)

#define MFMA __builtin_amdgcn_mfma_f32_16x16x32_bf16

// async global->LDS DMA, 16B per lane; LDS dest = uniform base + lane*16
#define ASYNC16(gp, lp)                                                        \
    __builtin_amdgcn_global_load_lds(                                          \
        (const __attribute__((address_space(1))) unsigned int*)(gp),           \
        (__attribute__((address_space(3))) unsigned int*)(lp), 16, 0, 0)

// ---------------------------------------------------------------------------
// cast_x: x[b][c][p] f32 -> Xt[b][p][c] bf16   (transpose via LDS)
// ---------------------------------------------------------------------------
__global__ __launch_bounds__(256) void cast_x(const float* __restrict__ x,
                                              __bf16* __restrict__ Xt)
{
    __shared__ float xs[64][65];
    const int t = threadIdx.x;
    const int p0 = blockIdx.x * 64;      // 64 tiles
    const int c0 = blockIdx.y * 64;      // 4 tiles
    const int b  = blockIdx.z;           // 4
#pragma unroll
    for (int k = 0; k < 16; ++k) {
        int e = t + k * 256, c = e >> 6, p = e & 63;
        xs[c][p] = x[((size_t)(b * CDIM + c0 + c)) * NTOK + p0 + p];
    }
    __syncthreads();
#pragma unroll
    for (int k = 0; k < 16; ++k) {
        int e = t + k * 256, p = e >> 6, c = e & 63;
        Xt[((size_t)(b * NTOK + p0 + p)) * CDIM + c0 + c] = (__bf16)xs[c][p];
    }
}

// ---------------------------------------------------------------------------
// cast_w: w_qkv (384x256) and w_out (256x128) f32 -> bf16
// ---------------------------------------------------------------------------
__global__ __launch_bounds__(256) void cast_w(const float* __restrict__ wq,
                                              const float* __restrict__ wo,
                                              __bf16* __restrict__ Wq,
                                              __bf16* __restrict__ Wo)
{
    int e = blockIdx.x * 256 + threadIdx.x;      // 512 blocks = 131072
    if (e < 384 * 256) Wq[e] = (__bf16)wq[e];
    else               Wo[e - 384 * 256] = (__bf16)wo[e - 384 * 256];
}

// ---------------------------------------------------------------------------
// qkv_gemm v7: DMA-staged.  Block = 128 p x 64 o (4 waves x 16 o), K=256.
// Xt tile (128x256 bf16 = 64 KB) DMA'd to LDS with 16B-chunk XOR swizzle
// (chunk lc at row p holds global chunk lc^(p&7)) -> frag ds_read_b128 are
// phase-balanced.  Weights: 8 register A-frags per wave, loaded up front.
//   Q,K: [bh][p][32] bf16 (Q pre-scaled);  Vt: [bh][32][4096] bf16
// ---------------------------------------------------------------------------
__global__ __launch_bounds__(256) void qkv_gemm(
    const __bf16* __restrict__ Wq, const __bf16* __restrict__ Xt,
    __bf16* __restrict__ Q, __bf16* __restrict__ K, __bf16* __restrict__ Vt)
{
    __shared__ __bf16 Xs[128 * 256];     // 64 KB, swizzled

    const int t  = threadIdx.x;
    const int pt = blockIdx.x;           // 32 (128 p each)
    const int ot = blockIdx.y;           // 6  (64 o each)
    const int b  = blockIdx.z;           // 4
    const int l = t & 63, lm = l & 15, q4 = l >> 4;
    const int w = __builtin_amdgcn_readfirstlane(t >> 6);
    const int p0 = pt * 128;
    const int o0w = ot * 64 + w * 16;

    // A fragments (weights): wave's 16 o-rows, all 8 k-chunks
    bf16x8 af[8];
#pragma unroll
    for (int kt = 0; kt < 8; ++kt)
        af[kt] = *(const bf16x8*)(Wq + (size_t)(o0w + lm) * CDIM + kt * 32 + q4 * 8);

    // DMA the Xt tile (swizzled gather): 16 instrs/wave, 1 KB each
#pragma unroll
    for (int i = 0; i < 16; ++i) {
        const int p_l = (i * 4 + w) * 2 + (l >> 5);
        const int gc  = (l & 31) ^ (p_l & 7);
        const __bf16* gp = Xt + ((size_t)(b * NTOK + p0 + p_l)) * CDIM + gc * 8;
        ASYNC16(gp, (char*)Xs + (i * 4 + w) * 1024);
    }
    __syncthreads();

    f32x4 acc[8] = {};
#pragma unroll
    for (int kt = 0; kt < 8; ++kt) {
#pragma unroll
        for (int nf = 0; nf < 8; ++nf) {
            const int p = nf * 16 + lm;
            bf16x8 bf = *(const bf16x8*)(
                (const char*)Xs + p * 512 + (((kt * 4 + q4) ^ (lm & 7)) * 16));
            acc[nf] = MFMA(af[kt], bf, acc[nf], 0, 0, 0);
        }
    }

    const int og0  = o0w + q4 * 4;       // r=0..3 stay in one head
    const int which = og0 >> 7;          // uniform per (ot,w)
    const int head  = (og0 >> 5) & 3;
    const int d0    = og0 & 31;
    const int bh    = b * HEADS + head;
#pragma unroll
    for (int nf = 0; nf < 8; ++nf) {
        const int p_g = p0 + nf * 16 + lm;
        f32x4 a = acc[nf];
        if (which == 0) {
            bf16x4 pk = { (__bf16)(a[0] * QSCALE), (__bf16)(a[1] * QSCALE),
                          (__bf16)(a[2] * QSCALE), (__bf16)(a[3] * QSCALE) };
            *(bf16x4*)(Q + ((size_t)bh * NTOK + p_g) * DHEAD + d0) = pk;
        } else if (which == 1) {
            bf16x4 pk = { (__bf16)a[0], (__bf16)a[1], (__bf16)a[2], (__bf16)a[3] };
            *(bf16x4*)(K + ((size_t)bh * NTOK + p_g) * DHEAD + d0) = pk;
        } else {
#pragma unroll
            for (int r = 0; r < 4; ++r)
                Vt[((size_t)(bh * DHEAD + d0 + r)) * NTOK + p_g] = (__bf16)a[r];
        }
    }
}

// ---------------------------------------------------------------------------
// attn v6 (unchanged): LDS-staged, double-buffered flash attention.
// ---------------------------------------------------------------------------
__global__ __launch_bounds__(256, 4) void attn(
    const __bf16* __restrict__ Q, const __bf16* __restrict__ K,
    const __bf16* __restrict__ Vt, float* __restrict__ Opart,
    float* __restrict__ Lsum)
{
    __shared__ uint4  KbufU[2][256];               // [buf][64 rows x 64 B]
    __shared__ uint4  VbufU[2][256];               // [buf][32 rows x 128 B]
    __shared__ __bf16 Ps[4][16][72];               // per-wave P rows (i=lm)

    const int t   = threadIdx.x;
    const int blk = blockIdx.x;                    // 1024
    const int bh  = blk & 15;
    const int rest = blk >> 4;                     // 0..63
    const int qt   = rest & 31;                    // 32 tiles of 128 rows
    const int half = rest >> 5;                    // j-split
    const int l = t & 63, lm = l & 15, q4 = l >> 4;
    const int wu = __builtin_amdgcn_readfirstlane(t >> 6);
    const int row0 = qt * 128 + wu * 32;

    bf16x8 qf[2];
#pragma unroll
    for (int g = 0; g < 2; ++g)
        qf[g] = *(const bf16x8*)(Q + ((size_t)bh * NTOK + row0 + g * 16 + lm) * DHEAD + q4 * 8);

    const char* KbT = (const char*)(K  + (size_t)bh * NTOK * DHEAD);
    const char* VbT = (const char*)(Vt + (size_t)bh * DHEAD * NTOK);
    const int jh = half * 2048;

    const int sK_r  = wu * 16 + (l >> 2);
    const int sK_gc = (l & 3) ^ ((sK_r >> 1) & 3);
    const int sV_r  = wu * 8 + (l >> 3);
    const int sV_gc = (l & 7) ^ (sV_r & 7);

    bf16x8 ones;
#pragma unroll
    for (int u = 0; u < 8; ++u) ones[u] = (__bf16)1.0f;

    f32x4 o[2][3] = {};

    {
        const char* gk = KbT + (size_t)(jh + sK_r) * 64 + sK_gc * 16;
        ASYNC16(gk, (char*)&KbufU[0][0] + wu * 1024);
        const char* gv = VbT + (size_t)sV_r * (NTOK * 2) + (size_t)jh * 2 + sV_gc * 16;
        ASYNC16(gv, (char*)&VbufU[0][0] + wu * 1024);
    }
    __syncthreads();

    for (int jt = 0; jt < 32; ++jt) {
        const int buf = jt & 1;
        if (jt < 31) {
            const int j0n = jh + (jt + 1) * 64;
            const char* gk = KbT + (size_t)(j0n + sK_r) * 64 + sK_gc * 16;
            ASYNC16(gk, (char*)&KbufU[buf ^ 1][0] + wu * 1024);
            const char* gv = VbT + (size_t)sV_r * (NTOK * 2) + (size_t)j0n * 2 + sV_gc * 16;
            ASYNC16(gv, (char*)&VbufU[buf ^ 1][0] + wu * 1024);
        }

        const __bf16* Kl = (const __bf16*)&KbufU[buf][0];
        const __bf16* Vl = (const __bf16*)&VbufU[buf][0];

        bf16x8 kf[4];
#pragma unroll
        for (int j4 = 0; j4 < 4; ++j4) {
            int jl = j4 * 16 + lm;
            int cs = q4 ^ ((jl >> 1) & 3);
            kf[j4] = *(const bf16x8*)(Kl + jl * 32 + cs * 8);
        }
        const int swv = lm & 7;
        bf16x8 vf[4];
        vf[0] = *(const bf16x8*)(Vl + lm * 64        + ((q4    ) ^ swv) * 8);
        vf[1] = *(const bf16x8*)(Vl + (16 + lm) * 64 + ((q4    ) ^ swv) * 8);
        vf[2] = *(const bf16x8*)(Vl + lm * 64        + ((4 + q4) ^ swv) * 8);
        vf[3] = *(const bf16x8*)(Vl + (16 + lm) * 64 + ((4 + q4) ^ swv) * 8);

#pragma unroll
        for (int g = 0; g < 2; ++g) {
            f32x4 st[4];
#pragma unroll
            for (int j4 = 0; j4 < 4; ++j4) {
                f32x4 z = {};
                st[j4] = MFMA(kf[j4], qf[g], z, 0, 0, 0);
            }
#pragma unroll
            for (int j4 = 0; j4 < 4; ++j4) {
                bf16x4 pk;
                pk[0] = (__bf16)__builtin_amdgcn_exp2f(st[j4][0]);
                pk[1] = (__bf16)__builtin_amdgcn_exp2f(st[j4][1]);
                pk[2] = (__bf16)__builtin_amdgcn_exp2f(st[j4][2]);
                pk[3] = (__bf16)__builtin_amdgcn_exp2f(st[j4][3]);
                *(bf16x4*)&Ps[wu][lm][j4 * 16 + q4 * 4] = pk;
            }
#pragma unroll
            for (int jc = 0; jc < 2; ++jc) {
                bf16x8 pf = *(const bf16x8*)&Ps[wu][lm][jc * 32 + q4 * 8];
                o[g][0] = MFMA(pf, vf[jc * 2 + 0], o[g][0], 0, 0, 0);
                o[g][1] = MFMA(pf, vf[jc * 2 + 1], o[g][1], 0, 0, 0);
                o[g][2] = MFMA(pf, ones,           o[g][2], 0, 0, 0);
            }
        }
        __syncthreads();
    }

    const int b = bh >> 2, h = bh & 3;
    float* Op = Opart + (size_t)half * NBATCH * NTOK * HID;
#pragma unroll
    for (int g = 0; g < 2; ++g) {
        const int rowg0 = row0 + g * 16;
        if (lm == 0)
            *(f32x4*)(Lsum + ((size_t)half * 16 + bh) * NTOK + rowg0 + q4 * 4) = o[g][2];
#pragma unroll
        for (int r = 0; r < 4; ++r) {
            size_t rowg = (size_t)b * NTOK + rowg0 + q4 * 4 + r;
            Op[rowg * HID + h * DHEAD + lm]      = o[g][0][r];
            Op[rowg * HID + h * DHEAD + 16 + lm] = o[g][1][r];
        }
    }
}

// ---------------------------------------------------------------------------
// combine: Obf[b,p,c] = bf16( (O0+O1)[b,p,c] / (L0+L1)[b,head(c),p] )
// pure-BW kernel (~42 MB), 8 elems/thread
// ---------------------------------------------------------------------------
__global__ __launch_bounds__(256) void combine(
    const float* __restrict__ O0, const float* __restrict__ O1,
    const float* __restrict__ L0, const float* __restrict__ L1,
    __bf16* __restrict__ Obf)
{
    const int e  = blockIdx.x * 256 + threadIdx.x;   // 1024 blocks
    const int c8 = e & 15;
    const int row = e >> 4;                          // b*NTOK + p
    const int p  = row & (NTOK - 1);
    const int b  = row >> 12;
    const int head = c8 >> 2;

    const size_t li = ((size_t)(b * HEADS + head)) * NTOK + p;
    const float inv = 1.f / (L0[li] + L1[li]);

    const size_t base = (size_t)row * HID + c8 * 8;
    f32x4 a0 = *(const f32x4*)(O0 + base);
    f32x4 a1 = *(const f32x4*)(O0 + base + 4);
    f32x4 c0 = *(const f32x4*)(O1 + base);
    f32x4 c1 = *(const f32x4*)(O1 + base + 4);
    bf16x8 o;
#pragma unroll
    for (int u = 0; u < 4; ++u) {
        o[u]     = (__bf16)((a0[u] + c0[u]) * inv);
        o[u + 4] = (__bf16)((a1[u] + c1[u]) * inv);
    }
    *(bf16x8*)(Obf + base) = o;
}

// ---------------------------------------------------------------------------
// out_gemm v7: DMA-staged.  Block = 128 p x 64 o, K=128.
// Obf tile (128x128 bf16 = 32 KB) DMA'd with the same XOR-chunk swizzle.
// out[b,o,p] = bias[o] + sum_c Wo[o,c] * Obf[b,p,c]
// ---------------------------------------------------------------------------
__global__ __launch_bounds__(256) void out_gemm(
    const __bf16* __restrict__ Wo, const __bf16* __restrict__ Obf,
    const float* __restrict__ bias, float* __restrict__ out)
{
    __shared__ __bf16 Bs[128 * 128];     // 32 KB, swizzled

    const int t  = threadIdx.x;
    const int pt = blockIdx.x;           // 32
    const int ot = blockIdx.y;           // 4 (64 o each)
    const int b  = blockIdx.z;           // 4
    const int l = t & 63, lm = l & 15, q4 = l >> 4;
    const int w = __builtin_amdgcn_readfirstlane(t >> 6);
    const int p0 = pt * 128;
    const int o0w = ot * 64 + w * 16;

    bf16x8 af[4];
#pragma unroll
    for (int kt = 0; kt < 4; ++kt)
        af[kt] = *(const bf16x8*)(Wo + (size_t)(o0w + lm) * HID + kt * 32 + q4 * 8);

#pragma unroll
    for (int i = 0; i < 8; ++i) {        // 32 KB: 8 instrs/wave
        const int p_l = (i * 4 + w) * 4 + (l >> 4);
        const int gc  = (l & 15) ^ (p_l & 7);
        const __bf16* gp = Obf + ((size_t)(b * NTOK + p0 + p_l)) * HID + gc * 8;
        ASYNC16(gp, (char*)Bs + (i * 4 + w) * 1024);
    }
    __syncthreads();

    f32x4 acc[8] = {};
#pragma unroll
    for (int kt = 0; kt < 4; ++kt) {
#pragma unroll
        for (int nf = 0; nf < 8; ++nf) {
            const int p = nf * 16 + lm;
            bf16x8 bf = *(const bf16x8*)(
                (const char*)Bs + p * 256 + (((kt * 4 + q4) ^ (lm & 7)) * 16));
            acc[nf] = MFMA(af[kt], bf, acc[nf], 0, 0, 0);
        }
    }

    const int og0 = o0w + q4 * 4;
#pragma unroll
    for (int nf = 0; nf < 8; ++nf) {
        const int p_g = p0 + nf * 16 + lm;
#pragma unroll
        for (int r = 0; r < 4; ++r)
            out[((size_t)(b * CDIM + og0 + r)) * NTOK + p_g] =
                acc[nf][r] + bias[og0 + r];
    }
}

// ---------------------------------------------------------------------------
extern "C" void kernel_launch(void* const* d_in, const int* in_sizes, int n_in,
                              void* d_out, int out_size, void* d_ws, size_t ws_size,
                              hipStream_t stream)
{
    const float* x     = (const float*)d_in[0];
    const float* w_qkv = (const float*)d_in[1];
    const float* w_out = (const float*)d_in[2];
    const float* b_out = (const float*)d_in[3];
    float* out = (float*)d_out;

    __bf16* Xt = (__bf16*)d_ws;                     // 8 MB
    __bf16* Wq = Xt + (size_t)NBATCH * NTOK * CDIM;
    __bf16* Wo = Wq + 384 * 256;
    __bf16* Q  = Wo + 256 * 128;                    // 4 MB each
    __bf16* K  = Q  + (size_t)16 * NTOK * DHEAD;
    __bf16* Vt = K  + (size_t)16 * NTOK * DHEAD;
    float*  Opart = (float*)(Vt + (size_t)16 * NTOK * DHEAD);  // 2 x 8 MB
    float*  Lsum  = Opart + (size_t)2 * NBATCH * NTOK * HID;   // 2 x 256 KB
    float*  L1p   = Lsum + (size_t)16 * NTOK;
    float*  O1p   = Opart + (size_t)NBATCH * NTOK * HID;
    __bf16* Obf   = (__bf16*)(L1p + (size_t)16 * NTOK);        // 4 MB

    cast_x  <<<dim3(64, 4, NBATCH), 256, 0, stream>>>(x, Xt);
    cast_w  <<<512, 256, 0, stream>>>(w_qkv, w_out, Wq, Wo);
    qkv_gemm<<<dim3(32, 6, NBATCH), 256, 0, stream>>>(Wq, Xt, Q, K, Vt);
    attn    <<<1024, 256, 0, stream>>>(Q, K, Vt, Opart, Lsum);
    combine <<<1024, 256, 0, stream>>>(Opart, O1p, Lsum, L1p, Obf);
    out_gemm<<<dim3(32, 4, NBATCH), 256, 0, stream>>>(Wo, Obf, b_out, out);
}

// Round 8
// 146.533 us; speedup vs baseline: 2.0097x; 1.0243x over previous
//
#include <hip/hip_runtime.h>
#include <stdint.h>

#define HEADS 4
#define DHEAD 32
#define NTOK  4096
#define CDIM  256
#define HID   128
#define NBATCH 4

typedef __bf16 bf16x8 __attribute__((ext_vector_type(8)));
typedef __bf16 bf16x4 __attribute__((ext_vector_type(4)));
typedef float  f32x4  __attribute__((ext_vector_type(4)));

// softmax scale folded with log2(e) into Q so scores are in base-2 domain
#define QSCALE (0.17677669529663689f * 1.4426950408889634f)

#define MFMA __builtin_amdgcn_mfma_f32_16x16x32_bf16

// async global->LDS DMA, 16B per lane; LDS dest = uniform base + lane*16
#define ASYNC16(gp, lp)                                                        \
    __builtin_amdgcn_global_load_lds(                                          \
        (const __attribute__((address_space(1))) unsigned int*)(gp),           \
        (__attribute__((address_space(3))) unsigned int*)(lp), 16, 0, 0)

// ---------------------------------------------------------------------------
// cast_x: x[b][c][p] f32 -> Xt[b][p][c] bf16   (transpose via LDS)
// ---------------------------------------------------------------------------
__global__ __launch_bounds__(256) void cast_x(const float* __restrict__ x,
                                              __bf16* __restrict__ Xt)
{
    __shared__ float xs[64][65];
    const int t = threadIdx.x;
    const int p0 = blockIdx.x * 64;      // 64 tiles
    const int c0 = blockIdx.y * 64;      // 4 tiles
    const int b  = blockIdx.z;           // 4
#pragma unroll
    for (int k = 0; k < 16; ++k) {
        int e = t + k * 256, c = e >> 6, p = e & 63;
        xs[c][p] = x[((size_t)(b * CDIM + c0 + c)) * NTOK + p0 + p];
    }
    __syncthreads();
#pragma unroll
    for (int k = 0; k < 16; ++k) {
        int e = t + k * 256, p = e >> 6, c = e & 63;
        Xt[((size_t)(b * NTOK + p0 + p)) * CDIM + c0 + c] = (__bf16)xs[c][p];
    }
}

// ---------------------------------------------------------------------------
// qkv_gemm: DMA-staged.  Block = 128 p x 64 o (4 waves x 16 o), K=256.
// A-frags built from fp32 weights (in-register cvt) -> no cast_w kernel.
// ---------------------------------------------------------------------------
__global__ __launch_bounds__(256) void qkv_gemm(
    const float* __restrict__ wq, const __bf16* __restrict__ Xt,
    __bf16* __restrict__ Q, __bf16* __restrict__ K, __bf16* __restrict__ Vt)
{
    __shared__ __bf16 Xs[128 * 256];     // 64 KB, swizzled

    const int t  = threadIdx.x;
    const int pt = blockIdx.x;           // 32 (128 p each)
    const int ot = blockIdx.y;           // 6  (64 o each)
    const int b  = blockIdx.z;           // 4
    const int l = t & 63, lm = l & 15, q4 = l >> 4;
    const int w = __builtin_amdgcn_readfirstlane(t >> 6);
    const int p0 = pt * 128;
    const int o0w = ot * 64 + w * 16;

    // DMA the Xt tile (swizzled gather): 16 instrs/wave, 1 KB each
#pragma unroll
    for (int i = 0; i < 16; ++i) {
        const int p_l = (i * 4 + w) * 2 + (l >> 5);
        const int gc  = (l & 31) ^ (p_l & 7);
        const __bf16* gp = Xt + ((size_t)(b * NTOK + p0 + p_l)) * CDIM + gc * 8;
        ASYNC16(gp, (char*)Xs + (i * 4 + w) * 1024);
    }

    // A fragments from fp32 weights (independent loads overlap the DMA)
    bf16x8 af[8];
#pragma unroll
    for (int kt = 0; kt < 8; ++kt) {
        const float* wr = wq + (size_t)(o0w + lm) * CDIM + kt * 32 + q4 * 8;
        f32x4 w0 = *(const f32x4*)wr;
        f32x4 w1 = *(const f32x4*)(wr + 4);
#pragma unroll
        for (int u = 0; u < 4; ++u) {
            af[kt][u]     = (__bf16)w0[u];
            af[kt][u + 4] = (__bf16)w1[u];
        }
    }
    __syncthreads();

    f32x4 acc[8] = {};
#pragma unroll
    for (int kt = 0; kt < 8; ++kt) {
#pragma unroll
        for (int nf = 0; nf < 8; ++nf) {
            const int p = nf * 16 + lm;
            bf16x8 bf = *(const bf16x8*)(
                (const char*)Xs + p * 512 + (((kt * 4 + q4) ^ (lm & 7)) * 16));
            acc[nf] = MFMA(af[kt], bf, acc[nf], 0, 0, 0);
        }
    }

    const int og0  = o0w + q4 * 4;       // r=0..3 stay in one head
    const int which = og0 >> 7;          // uniform per (ot,w)
    const int head  = (og0 >> 5) & 3;
    const int d0    = og0 & 31;
    const int bh    = b * HEADS + head;
#pragma unroll
    for (int nf = 0; nf < 8; ++nf) {
        const int p_g = p0 + nf * 16 + lm;
        f32x4 a = acc[nf];
        if (which == 0) {
            bf16x4 pk = { (__bf16)(a[0] * QSCALE), (__bf16)(a[1] * QSCALE),
                          (__bf16)(a[2] * QSCALE), (__bf16)(a[3] * QSCALE) };
            *(bf16x4*)(Q + ((size_t)bh * NTOK + p_g) * DHEAD + d0) = pk;
        } else if (which == 1) {
            bf16x4 pk = { (__bf16)a[0], (__bf16)a[1], (__bf16)a[2], (__bf16)a[3] };
            *(bf16x4*)(K + ((size_t)bh * NTOK + p_g) * DHEAD + d0) = pk;
        } else {
#pragma unroll
            for (int r = 0; r < 4; ++r)
                Vt[((size_t)(bh * DHEAD + d0 + r)) * NTOK + p_g] = (__bf16)a[r];
        }
    }
}

// ---------------------------------------------------------------------------
// attn: LDS-staged, double-buffered flash attention, split-j x3.
// 1536 blocks = 6 blocks/CU (LDS-capped, 153.6/160 KB).  Partial O spilled
// as bf16 (accumulation stays fp32 in AGPRs); Lsum fp32 via ones-MFMA.
// ---------------------------------------------------------------------------
__global__ __launch_bounds__(256, 4) void attn(
    const __bf16* __restrict__ Q, const __bf16* __restrict__ K,
    const __bf16* __restrict__ Vt, __bf16* __restrict__ Opart,
    float* __restrict__ Lsum)
{
    __shared__ uint4  KbufU[2][256];               // [buf][64 rows x 64 B]
    __shared__ uint4  VbufU[2][256];               // [buf][32 rows x 128 B]
    __shared__ __bf16 Ps[4][16][72];               // per-wave P rows (i=lm)

    const int t   = threadIdx.x;
    const int blk = blockIdx.x;                    // 1536
    const int bh  = blk & 15;
    const int rest = blk >> 4;                     // 0..95
    const int qt   = rest & 31;                    // 32 tiles of 128 rows
    const int sp   = rest >> 5;                    // j-split 0..2
    const int l = t & 63, lm = l & 15, q4 = l >> 4;
    const int wu = __builtin_amdgcn_readfirstlane(t >> 6);
    const int row0 = qt * 128 + wu * 32;

    // j-tile ranges: [0,22) [22,43) [43,64)
    const int jt0 = sp * 21 + (sp > 0 ? 1 : 0);
    const int jt1 = jt0 + 21 + (sp == 0 ? 1 : 0);

    bf16x8 qf[2];
#pragma unroll
    for (int g = 0; g < 2; ++g)
        qf[g] = *(const bf16x8*)(Q + ((size_t)bh * NTOK + row0 + g * 16 + lm) * DHEAD + q4 * 8);

    const char* KbT = (const char*)(K  + (size_t)bh * NTOK * DHEAD);
    const char* VbT = (const char*)(Vt + (size_t)bh * DHEAD * NTOK);

    const int sK_r  = wu * 16 + (l >> 2);
    const int sK_gc = (l & 3) ^ ((sK_r >> 1) & 3);
    const int sV_r  = wu * 8 + (l >> 3);
    const int sV_gc = (l & 7) ^ (sV_r & 7);

    bf16x8 ones;
#pragma unroll
    for (int u = 0; u < 8; ++u) ones[u] = (__bf16)1.0f;

    f32x4 o[2][3] = {};

    {
        const int j00 = jt0 * 64;
        const char* gk = KbT + (size_t)(j00 + sK_r) * 64 + sK_gc * 16;
        ASYNC16(gk, (char*)&KbufU[0][0] + wu * 1024);
        const char* gv = VbT + (size_t)sV_r * (NTOK * 2) + (size_t)j00 * 2 + sV_gc * 16;
        ASYNC16(gv, (char*)&VbufU[0][0] + wu * 1024);
    }
    __syncthreads();

    for (int jt = jt0; jt < jt1; ++jt) {
        const int buf = (jt - jt0) & 1;
        if (jt + 1 < jt1) {
            const int j0n = (jt + 1) * 64;
            const char* gk = KbT + (size_t)(j0n + sK_r) * 64 + sK_gc * 16;
            ASYNC16(gk, (char*)&KbufU[buf ^ 1][0] + wu * 1024);
            const char* gv = VbT + (size_t)sV_r * (NTOK * 2) + (size_t)j0n * 2 + sV_gc * 16;
            ASYNC16(gv, (char*)&VbufU[buf ^ 1][0] + wu * 1024);
        }

        const __bf16* Kl = (const __bf16*)&KbufU[buf][0];
        const __bf16* Vl = (const __bf16*)&VbufU[buf][0];

        bf16x8 kf[4];
#pragma unroll
        for (int j4 = 0; j4 < 4; ++j4) {
            int jl = j4 * 16 + lm;
            int cs = q4 ^ ((jl >> 1) & 3);
            kf[j4] = *(const bf16x8*)(Kl + jl * 32 + cs * 8);
        }
        const int swv = lm & 7;
        bf16x8 vf[4];
        vf[0] = *(const bf16x8*)(Vl + lm * 64        + ((q4    ) ^ swv) * 8);
        vf[1] = *(const bf16x8*)(Vl + (16 + lm) * 64 + ((q4    ) ^ swv) * 8);
        vf[2] = *(const bf16x8*)(Vl + lm * 64        + ((4 + q4) ^ swv) * 8);
        vf[3] = *(const bf16x8*)(Vl + (16 + lm) * 64 + ((4 + q4) ^ swv) * 8);

#pragma unroll
        for (int g = 0; g < 2; ++g) {
            f32x4 st[4];
#pragma unroll
            for (int j4 = 0; j4 < 4; ++j4) {
                f32x4 z = {};
                st[j4] = MFMA(kf[j4], qf[g], z, 0, 0, 0);
            }
#pragma unroll
            for (int j4 = 0; j4 < 4; ++j4) {
                bf16x4 pk;
                pk[0] = (__bf16)__builtin_amdgcn_exp2f(st[j4][0]);
                pk[1] = (__bf16)__builtin_amdgcn_exp2f(st[j4][1]);
                pk[2] = (__bf16)__builtin_amdgcn_exp2f(st[j4][2]);
                pk[3] = (__bf16)__builtin_amdgcn_exp2f(st[j4][3]);
                *(bf16x4*)&Ps[wu][lm][j4 * 16 + q4 * 4] = pk;
            }
#pragma unroll
            for (int jc = 0; jc < 2; ++jc) {
                bf16x8 pf = *(const bf16x8*)&Ps[wu][lm][jc * 32 + q4 * 8];
                o[g][0] = MFMA(pf, vf[jc * 2 + 0], o[g][0], 0, 0, 0);
                o[g][1] = MFMA(pf, vf[jc * 2 + 1], o[g][1], 0, 0, 0);
                o[g][2] = MFMA(pf, ones,           o[g][2], 0, 0, 0);
            }
        }
        __syncthreads();
    }

    const int b = bh >> 2, h = bh & 3;
    __bf16* Op = Opart + (size_t)sp * NBATCH * NTOK * HID;
#pragma unroll
    for (int g = 0; g < 2; ++g) {
        const int rowg0 = row0 + g * 16;
        if (lm == 0)
            *(f32x4*)(Lsum + ((size_t)sp * 16 + bh) * NTOK + rowg0 + q4 * 4) = o[g][2];
#pragma unroll
        for (int r = 0; r < 4; ++r) {
            size_t rowg = (size_t)b * NTOK + rowg0 + q4 * 4 + r;
            Op[rowg * HID + h * DHEAD + lm]      = (__bf16)o[g][0][r];
            Op[rowg * HID + h * DHEAD + 16 + lm] = (__bf16)o[g][1][r];
        }
    }
}

// ---------------------------------------------------------------------------
// combine: Obf[b,p,c] = bf16( sum_sp P_sp[b,p,c] / sum_sp L_sp[b,head(c),p] )
// ---------------------------------------------------------------------------
__global__ __launch_bounds__(256) void combine(
    const __bf16* __restrict__ Opart, const float* __restrict__ Lsum,
    __bf16* __restrict__ Obf)
{
    const int e  = blockIdx.x * 256 + threadIdx.x;   // 1024 blocks
    const int c8 = e & 15;
    const int row = e >> 4;                          // b*NTOK + p
    const int p  = row & (NTOK - 1);
    const int b  = row >> 12;
    const int head = c8 >> 2;

    const size_t li = ((size_t)(b * HEADS + head)) * NTOK + p;
    const float inv = 1.f / (Lsum[li] + Lsum[li + 16 * NTOK] + Lsum[li + 32 * NTOK]);

    const size_t per = (size_t)NBATCH * NTOK * HID;
    const size_t base = (size_t)row * HID + c8 * 8;
    bf16x8 x0 = *(const bf16x8*)(Opart + base);
    bf16x8 x1 = *(const bf16x8*)(Opart + per + base);
    bf16x8 x2 = *(const bf16x8*)(Opart + 2 * per + base);
    bf16x8 o;
#pragma unroll
    for (int u = 0; u < 8; ++u)
        o[u] = (__bf16)(((float)x0[u] + (float)x1[u] + (float)x2[u]) * inv);
    *(bf16x8*)(Obf + base) = o;
}

// ---------------------------------------------------------------------------
// out_gemm: DMA-staged.  Block = 128 p x 64 o, K=128; fp32 weights in-reg cvt.
// out[b,o,p] = bias[o] + sum_c Wo[o,c] * Obf[b,p,c]
// ---------------------------------------------------------------------------
__global__ __launch_bounds__(256) void out_gemm(
    const float* __restrict__ wo, const __bf16* __restrict__ Obf,
    const float* __restrict__ bias, float* __restrict__ out)
{
    __shared__ __bf16 Bs[128 * 128];     // 32 KB, swizzled

    const int t  = threadIdx.x;
    const int pt = blockIdx.x;           // 32
    const int ot = blockIdx.y;           // 4 (64 o each)
    const int b  = blockIdx.z;           // 4
    const int l = t & 63, lm = l & 15, q4 = l >> 4;
    const int w = __builtin_amdgcn_readfirstlane(t >> 6);
    const int p0 = pt * 128;
    const int o0w = ot * 64 + w * 16;

#pragma unroll
    for (int i = 0; i < 8; ++i) {        // 32 KB: 8 instrs/wave
        const int p_l = (i * 4 + w) * 4 + (l >> 4);
        const int gc  = (l & 15) ^ (p_l & 7);
        const __bf16* gp = Obf + ((size_t)(b * NTOK + p0 + p_l)) * HID + gc * 8;
        ASYNC16(gp, (char*)Bs + (i * 4 + w) * 1024);
    }

    bf16x8 af[4];
#pragma unroll
    for (int kt = 0; kt < 4; ++kt) {
        const float* wr = wo + (size_t)(o0w + lm) * HID + kt * 32 + q4 * 8;
        f32x4 w0 = *(const f32x4*)wr;
        f32x4 w1 = *(const f32x4*)(wr + 4);
#pragma unroll
        for (int u = 0; u < 4; ++u) {
            af[kt][u]     = (__bf16)w0[u];
            af[kt][u + 4] = (__bf16)w1[u];
        }
    }
    __syncthreads();

    f32x4 acc[8] = {};
#pragma unroll
    for (int kt = 0; kt < 4; ++kt) {
#pragma unroll
        for (int nf = 0; nf < 8; ++nf) {
            const int p = nf * 16 + lm;
            bf16x8 bf = *(const bf16x8*)(
                (const char*)Bs + p * 256 + (((kt * 4 + q4) ^ (lm & 7)) * 16));
            acc[nf] = MFMA(af[kt], bf, acc[nf], 0, 0, 0);
        }
    }

    const int og0 = o0w + q4 * 4;
#pragma unroll
    for (int nf = 0; nf < 8; ++nf) {
        const int p_g = p0 + nf * 16 + lm;
#pragma unroll
        for (int r = 0; r < 4; ++r)
            out[((size_t)(b * CDIM + og0 + r)) * NTOK + p_g] =
                acc[nf][r] + bias[og0 + r];
    }
}

// ---------------------------------------------------------------------------
extern "C" void kernel_launch(void* const* d_in, const int* in_sizes, int n_in,
                              void* d_out, int out_size, void* d_ws, size_t ws_size,
                              hipStream_t stream)
{
    const float* x     = (const float*)d_in[0];
    const float* w_qkv = (const float*)d_in[1];
    const float* w_out = (const float*)d_in[2];
    const float* b_out = (const float*)d_in[3];
    float* out = (float*)d_out;

    __bf16* Xt = (__bf16*)d_ws;                           // 8 MB
    __bf16* Q  = Xt + (size_t)NBATCH * NTOK * CDIM;       // 4 MB each
    __bf16* K  = Q  + (size_t)16 * NTOK * DHEAD;
    __bf16* Vt = K  + (size_t)16 * NTOK * DHEAD;
    __bf16* Opart = Vt + (size_t)16 * NTOK * DHEAD;       // 3 x 4 MB (bf16)
    __bf16* Obf   = Opart + (size_t)3 * NBATCH * NTOK * HID;   // 4 MB
    float*  Lsum  = (float*)(Obf + (size_t)NBATCH * NTOK * HID); // 3 x 256 KB

    cast_x  <<<dim3(64, 4, NBATCH), 256, 0, stream>>>(x, Xt);
    qkv_gemm<<<dim3(32, 6, NBATCH), 256, 0, stream>>>(w_qkv, Xt, Q, K, Vt);
    attn    <<<1536, 256, 0, stream>>>(Q, K, Vt, Opart, Lsum);
    combine <<<1024, 256, 0, stream>>>(Opart, Lsum, Obf);
    out_gemm<<<dim3(32, 4, NBATCH), 256, 0, stream>>>(w_out, Obf, b_out, out);
}

// Round 9
// 145.834 us; speedup vs baseline: 2.0193x; 1.0048x over previous
//
#include <hip/hip_runtime.h>
#include <stdint.h>

#define HEADS 4
#define DHEAD 32
#define NTOK  4096
#define CDIM  256
#define HID   128
#define NBATCH 4

typedef __bf16 bf16x8 __attribute__((ext_vector_type(8)));
typedef __bf16 bf16x4 __attribute__((ext_vector_type(4)));
typedef float  f32x4  __attribute__((ext_vector_type(4)));

// softmax scale folded with log2(e) into Q so scores are in base-2 domain
#define QSCALE (0.17677669529663689f * 1.4426950408889634f)

#define MFMA __builtin_amdgcn_mfma_f32_16x16x32_bf16

// async global->LDS DMA, 16B per lane; LDS dest = uniform base + lane*16
#define ASYNC16(gp, lp)                                                        \
    __builtin_amdgcn_global_load_lds(                                          \
        (const __attribute__((address_space(1))) unsigned int*)(gp),           \
        (__attribute__((address_space(3))) unsigned int*)(lp), 16, 0, 0)

// ---------------------------------------------------------------------------
// cast_x: x[b][c][p] f32 -> Xt[b][p][c] bf16.  Vectorized: float4 global
// reads, bf16x8 (16B) global stores; LDS transpose with 2-way (free) banking.
// ---------------------------------------------------------------------------
__global__ __launch_bounds__(256) void cast_x(const float* __restrict__ x,
                                              __bf16* __restrict__ Xt)
{
    __shared__ float xs[64][65];
    const int t = threadIdx.x;
    const int p0 = blockIdx.x * 64;      // 64 tiles
    const int c0 = blockIdx.y * 64;      // 4 tiles
    const int b  = blockIdx.z;           // 4

    const int p4 = (t & 15) * 4;
#pragma unroll
    for (int k = 0; k < 4; ++k) {        // float4 coalesced reads
        const int c = (t >> 4) + k * 16;
        f32x4 v = *(const f32x4*)(x + ((size_t)(b * CDIM + c0 + c)) * NTOK + p0 + p4);
#pragma unroll
        for (int i = 0; i < 4; ++i) xs[c][p4 + i] = v[i];   // 2-way banks: free
    }
    __syncthreads();

    const int c8 = t & 7;
#pragma unroll
    for (int m = 0; m < 2; ++m) {
        const int p = (t >> 3) + m * 32;
        bf16x8 o;
#pragma unroll
        for (int u = 0; u < 8; ++u) o[u] = (__bf16)xs[c8 * 8 + u][p];  // 2-way: free
        *(bf16x8*)(Xt + ((size_t)(b * NTOK + p0 + p)) * CDIM + c0 + c8 * 8) = o;
    }
}

// ---------------------------------------------------------------------------
// qkv_gemm: DMA-staged.  Block = 128 p x 64 o (4 waves x 16 o), K=256.
// A-frags built from fp32 weights (in-register cvt) -> no cast_w kernel.
// ---------------------------------------------------------------------------
__global__ __launch_bounds__(256) void qkv_gemm(
    const float* __restrict__ wq, const __bf16* __restrict__ Xt,
    __bf16* __restrict__ Q, __bf16* __restrict__ K, __bf16* __restrict__ Vt)
{
    __shared__ __bf16 Xs[128 * 256];     // 64 KB, swizzled

    const int t  = threadIdx.x;
    const int pt = blockIdx.x;           // 32 (128 p each)
    const int ot = blockIdx.y;           // 6  (64 o each)
    const int b  = blockIdx.z;           // 4
    const int l = t & 63, lm = l & 15, q4 = l >> 4;
    const int w = __builtin_amdgcn_readfirstlane(t >> 6);
    const int p0 = pt * 128;
    const int o0w = ot * 64 + w * 16;

    // DMA the Xt tile (swizzled gather): 16 instrs/wave, 1 KB each
#pragma unroll
    for (int i = 0; i < 16; ++i) {
        const int p_l = (i * 4 + w) * 2 + (l >> 5);
        const int gc  = (l & 31) ^ (p_l & 7);
        const __bf16* gp = Xt + ((size_t)(b * NTOK + p0 + p_l)) * CDIM + gc * 8;
        ASYNC16(gp, (char*)Xs + (i * 4 + w) * 1024);
    }

    // A fragments from fp32 weights (independent loads overlap the DMA)
    bf16x8 af[8];
#pragma unroll
    for (int kt = 0; kt < 8; ++kt) {
        const float* wr = wq + (size_t)(o0w + lm) * CDIM + kt * 32 + q4 * 8;
        f32x4 w0 = *(const f32x4*)wr;
        f32x4 w1 = *(const f32x4*)(wr + 4);
#pragma unroll
        for (int u = 0; u < 4; ++u) {
            af[kt][u]     = (__bf16)w0[u];
            af[kt][u + 4] = (__bf16)w1[u];
        }
    }
    __syncthreads();

    f32x4 acc[8] = {};
#pragma unroll
    for (int kt = 0; kt < 8; ++kt) {
#pragma unroll
        for (int nf = 0; nf < 8; ++nf) {
            const int p = nf * 16 + lm;
            bf16x8 bf = *(const bf16x8*)(
                (const char*)Xs + p * 512 + (((kt * 4 + q4) ^ (lm & 7)) * 16));
            acc[nf] = MFMA(af[kt], bf, acc[nf], 0, 0, 0);
        }
    }

    const int og0  = o0w + q4 * 4;       // r=0..3 stay in one head
    const int which = og0 >> 7;          // uniform per (ot,w)
    const int head  = (og0 >> 5) & 3;
    const int d0    = og0 & 31;
    const int bh    = b * HEADS + head;
#pragma unroll
    for (int nf = 0; nf < 8; ++nf) {
        const int p_g = p0 + nf * 16 + lm;
        f32x4 a = acc[nf];
        if (which == 0) {
            bf16x4 pk = { (__bf16)(a[0] * QSCALE), (__bf16)(a[1] * QSCALE),
                          (__bf16)(a[2] * QSCALE), (__bf16)(a[3] * QSCALE) };
            *(bf16x4*)(Q + ((size_t)bh * NTOK + p_g) * DHEAD + d0) = pk;
        } else if (which == 1) {
            bf16x4 pk = { (__bf16)a[0], (__bf16)a[1], (__bf16)a[2], (__bf16)a[3] };
            *(bf16x4*)(K + ((size_t)bh * NTOK + p_g) * DHEAD + d0) = pk;
        } else {
#pragma unroll
            for (int r = 0; r < 4; ++r)
                Vt[((size_t)(bh * DHEAD + d0 + r)) * NTOK + p_g] = (__bf16)a[r];
        }
    }
}

// ---------------------------------------------------------------------------
// attn: LDS-staged, double-buffered flash attention, split-j x4, g=4 row
// groups per wave (256 Q rows/block).  K/V staged once per block per j-tile;
// fragment reads amortized over 4 row-groups; 40 MFMAs per wave-iter.
// Partial O spilled as bf16; row-sums via ones-MFMA (fp32).
// ---------------------------------------------------------------------------
__global__ __launch_bounds__(256, 4) void attn(
    const __bf16* __restrict__ Q, const __bf16* __restrict__ K,
    const __bf16* __restrict__ Vt, __bf16* __restrict__ Opart,
    float* __restrict__ Lsum)
{
    __shared__ uint4  KbufU[2][256];               // [buf][64 rows x 64 B]
    __shared__ uint4  VbufU[2][256];               // [buf][32 rows x 128 B]
    __shared__ __bf16 Ps[4][16][72];               // per-wave P rows (i=lm)

    const int t   = threadIdx.x;
    const int blk = blockIdx.x;                    // 1024
    const int bh  = blk & 15;
    const int rest = blk >> 4;                     // 0..63
    const int qt   = rest & 15;                    // 16 tiles of 256 rows
    const int sp   = rest >> 4;                    // j-split 0..3
    const int l = t & 63, lm = l & 15, q4 = l >> 4;
    const int wu = __builtin_amdgcn_readfirstlane(t >> 6);
    const int row0 = qt * 256 + wu * 64;

    const int jt0 = sp * 16, jt1 = jt0 + 16;

    bf16x8 qf[4];
#pragma unroll
    for (int g = 0; g < 4; ++g)
        qf[g] = *(const bf16x8*)(Q + ((size_t)bh * NTOK + row0 + g * 16 + lm) * DHEAD + q4 * 8);

    const char* KbT = (const char*)(K  + (size_t)bh * NTOK * DHEAD);
    const char* VbT = (const char*)(Vt + (size_t)bh * DHEAD * NTOK);

    const int sK_r  = wu * 16 + (l >> 2);
    const int sK_gc = (l & 3) ^ ((sK_r >> 1) & 3);
    const int sV_r  = wu * 8 + (l >> 3);
    const int sV_gc = (l & 7) ^ (sV_r & 7);

    bf16x8 ones;
#pragma unroll
    for (int u = 0; u < 8; ++u) ones[u] = (__bf16)1.0f;

    f32x4 o[4][3] = {};

    {
        const int j00 = jt0 * 64;
        const char* gk = KbT + (size_t)(j00 + sK_r) * 64 + sK_gc * 16;
        ASYNC16(gk, (char*)&KbufU[0][0] + wu * 1024);
        const char* gv = VbT + (size_t)sV_r * (NTOK * 2) + (size_t)j00 * 2 + sV_gc * 16;
        ASYNC16(gv, (char*)&VbufU[0][0] + wu * 1024);
    }
    __syncthreads();

    for (int jt = jt0; jt < jt1; ++jt) {
        const int buf = (jt - jt0) & 1;
        if (jt + 1 < jt1) {
            const int j0n = (jt + 1) * 64;
            const char* gk = KbT + (size_t)(j0n + sK_r) * 64 + sK_gc * 16;
            ASYNC16(gk, (char*)&KbufU[buf ^ 1][0] + wu * 1024);
            const char* gv = VbT + (size_t)sV_r * (NTOK * 2) + (size_t)j0n * 2 + sV_gc * 16;
            ASYNC16(gv, (char*)&VbufU[buf ^ 1][0] + wu * 1024);
        }

        const __bf16* Kl = (const __bf16*)&KbufU[buf][0];
        const __bf16* Vl = (const __bf16*)&VbufU[buf][0];

        bf16x8 kf[4];
#pragma unroll
        for (int j4 = 0; j4 < 4; ++j4) {
            int jl = j4 * 16 + lm;
            int cs = q4 ^ ((jl >> 1) & 3);
            kf[j4] = *(const bf16x8*)(Kl + jl * 32 + cs * 8);
        }
        const int swv = lm & 7;
        bf16x8 vf[4];
        vf[0] = *(const bf16x8*)(Vl + lm * 64        + ((q4    ) ^ swv) * 8);
        vf[1] = *(const bf16x8*)(Vl + (16 + lm) * 64 + ((q4    ) ^ swv) * 8);
        vf[2] = *(const bf16x8*)(Vl + lm * 64        + ((4 + q4) ^ swv) * 8);
        vf[3] = *(const bf16x8*)(Vl + (16 + lm) * 64 + ((4 + q4) ^ swv) * 8);

#pragma unroll
        for (int g = 0; g < 4; ++g) {
            f32x4 st[4];
#pragma unroll
            for (int j4 = 0; j4 < 4; ++j4) {
                f32x4 z = {};
                st[j4] = MFMA(kf[j4], qf[g], z, 0, 0, 0);
            }
#pragma unroll
            for (int j4 = 0; j4 < 4; ++j4) {
                bf16x4 pk;
                pk[0] = (__bf16)__builtin_amdgcn_exp2f(st[j4][0]);
                pk[1] = (__bf16)__builtin_amdgcn_exp2f(st[j4][1]);
                pk[2] = (__bf16)__builtin_amdgcn_exp2f(st[j4][2]);
                pk[3] = (__bf16)__builtin_amdgcn_exp2f(st[j4][3]);
                *(bf16x4*)&Ps[wu][lm][j4 * 16 + q4 * 4] = pk;
            }
#pragma unroll
            for (int jc = 0; jc < 2; ++jc) {
                bf16x8 pf = *(const bf16x8*)&Ps[wu][lm][jc * 32 + q4 * 8];
                o[g][0] = MFMA(pf, vf[jc * 2 + 0], o[g][0], 0, 0, 0);
                o[g][1] = MFMA(pf, vf[jc * 2 + 1], o[g][1], 0, 0, 0);
                o[g][2] = MFMA(pf, ones,           o[g][2], 0, 0, 0);
            }
        }
        __syncthreads();
    }

    const int b = bh >> 2, h = bh & 3;
    __bf16* Op = Opart + (size_t)sp * NBATCH * NTOK * HID;
#pragma unroll
    for (int g = 0; g < 4; ++g) {
        const int rowg0 = row0 + g * 16;
        if (lm == 0)
            *(f32x4*)(Lsum + ((size_t)sp * 16 + bh) * NTOK + rowg0 + q4 * 4) = o[g][2];
#pragma unroll
        for (int r = 0; r < 4; ++r) {
            size_t rowg = (size_t)b * NTOK + rowg0 + q4 * 4 + r;
            Op[rowg * HID + h * DHEAD + lm]      = (__bf16)o[g][0][r];
            Op[rowg * HID + h * DHEAD + 16 + lm] = (__bf16)o[g][1][r];
        }
    }
}

// ---------------------------------------------------------------------------
// combine: Obf[b,p,c] = bf16( sum_sp P_sp[b,p,c] / sum_sp L_sp[b,head(c),p] )
// ---------------------------------------------------------------------------
__global__ __launch_bounds__(256) void combine(
    const __bf16* __restrict__ Opart, const float* __restrict__ Lsum,
    __bf16* __restrict__ Obf)
{
    const int e  = blockIdx.x * 256 + threadIdx.x;   // 1024 blocks
    const int c8 = e & 15;
    const int row = e >> 4;                          // b*NTOK + p
    const int p  = row & (NTOK - 1);
    const int b  = row >> 12;
    const int head = c8 >> 2;

    const size_t li = ((size_t)(b * HEADS + head)) * NTOK + p;
    const float inv = 1.f / (Lsum[li] + Lsum[li + 16 * NTOK] +
                             Lsum[li + 32 * NTOK] + Lsum[li + 48 * NTOK]);

    const size_t per = (size_t)NBATCH * NTOK * HID;
    const size_t base = (size_t)row * HID + c8 * 8;
    bf16x8 x0 = *(const bf16x8*)(Opart + base);
    bf16x8 x1 = *(const bf16x8*)(Opart + per + base);
    bf16x8 x2 = *(const bf16x8*)(Opart + 2 * per + base);
    bf16x8 x3 = *(const bf16x8*)(Opart + 3 * per + base);
    bf16x8 o;
#pragma unroll
    for (int u = 0; u < 8; ++u)
        o[u] = (__bf16)((((float)x0[u] + (float)x1[u]) +
                         ((float)x2[u] + (float)x3[u])) * inv);
    *(bf16x8*)(Obf + base) = o;
}

// ---------------------------------------------------------------------------
// out_gemm: DMA-staged.  Block = 128 p x 64 o, K=128; fp32 weights in-reg cvt.
// out[b,o,p] = bias[o] + sum_c Wo[o,c] * Obf[b,p,c]
// ---------------------------------------------------------------------------
__global__ __launch_bounds__(256) void out_gemm(
    const float* __restrict__ wo, const __bf16* __restrict__ Obf,
    const float* __restrict__ bias, float* __restrict__ out)
{
    __shared__ __bf16 Bs[128 * 128];     // 32 KB, swizzled

    const int t  = threadIdx.x;
    const int pt = blockIdx.x;           // 32
    const int ot = blockIdx.y;           // 4 (64 o each)
    const int b  = blockIdx.z;           // 4
    const int l = t & 63, lm = l & 15, q4 = l >> 4;
    const int w = __builtin_amdgcn_readfirstlane(t >> 6);
    const int p0 = pt * 128;
    const int o0w = ot * 64 + w * 16;

#pragma unroll
    for (int i = 0; i < 8; ++i) {        // 32 KB: 8 instrs/wave
        const int p_l = (i * 4 + w) * 4 + (l >> 4);
        const int gc  = (l & 15) ^ (p_l & 7);
        const __bf16* gp = Obf + ((size_t)(b * NTOK + p0 + p_l)) * HID + gc * 8;
        ASYNC16(gp, (char*)Bs + (i * 4 + w) * 1024);
    }

    bf16x8 af[4];
#pragma unroll
    for (int kt = 0; kt < 4; ++kt) {
        const float* wr = wo + (size_t)(o0w + lm) * HID + kt * 32 + q4 * 8;
        f32x4 w0 = *(const f32x4*)wr;
        f32x4 w1 = *(const f32x4*)(wr + 4);
#pragma unroll
        for (int u = 0; u < 4; ++u) {
            af[kt][u]     = (__bf16)w0[u];
            af[kt][u + 4] = (__bf16)w1[u];
        }
    }
    __syncthreads();

    f32x4 acc[8] = {};
#pragma unroll
    for (int kt = 0; kt < 4; ++kt) {
#pragma unroll
        for (int nf = 0; nf < 8; ++nf) {
            const int p = nf * 16 + lm;
            bf16x8 bf = *(const bf16x8*)(
                (const char*)Bs + p * 256 + (((kt * 4 + q4) ^ (lm & 7)) * 16));
            acc[nf] = MFMA(af[kt], bf, acc[nf], 0, 0, 0);
        }
    }

    const int og0 = o0w + q4 * 4;
#pragma unroll
    for (int nf = 0; nf < 8; ++nf) {
        const int p_g = p0 + nf * 16 + lm;
#pragma unroll
        for (int r = 0; r < 4; ++r)
            out[((size_t)(b * CDIM + og0 + r)) * NTOK + p_g] =
                acc[nf][r] + bias[og0 + r];
    }
}

// ---------------------------------------------------------------------------
extern "C" void kernel_launch(void* const* d_in, const int* in_sizes, int n_in,
                              void* d_out, int out_size, void* d_ws, size_t ws_size,
                              hipStream_t stream)
{
    const float* x     = (const float*)d_in[0];
    const float* w_qkv = (const float*)d_in[1];
    const float* w_out = (const float*)d_in[2];
    const float* b_out = (const float*)d_in[3];
    float* out = (float*)d_out;

    __bf16* Xt = (__bf16*)d_ws;                           // 8 MB
    __bf16* Q  = Xt + (size_t)NBATCH * NTOK * CDIM;       // 4 MB each
    __bf16* K  = Q  + (size_t)16 * NTOK * DHEAD;
    __bf16* Vt = K  + (size_t)16 * NTOK * DHEAD;
    __bf16* Opart = Vt + (size_t)16 * NTOK * DHEAD;       // 4 x 4 MB (bf16)
    __bf16* Obf   = Opart + (size_t)4 * NBATCH * NTOK * HID;   // 4 MB
    float*  Lsum  = (float*)(Obf + (size_t)NBATCH * NTOK * HID); // 4 x 256 KB

    cast_x  <<<dim3(64, 4, NBATCH), 256, 0, stream>>>(x, Xt);
    qkv_gemm<<<dim3(32, 6, NBATCH), 256, 0, stream>>>(w_qkv, Xt, Q, K, Vt);
    attn    <<<1024, 256, 0, stream>>>(Q, K, Vt, Opart, Lsum);
    combine <<<1024, 256, 0, stream>>>(Opart, Lsum, Obf);
    out_gemm<<<dim3(32, 4, NBATCH), 256, 0, stream>>>(w_out, Obf, b_out, out);
}